// Round 7
// baseline (1774.207 us; speedup 1.0000x reference)
//
#include <hip/hip_runtime.h>
#include <hip/hip_bf16.h>
#include <stdint.h>

// ---------------------------------------------------------------------------
// Informer encoder forward (B=8,S=1024,D=512,H=8,Dh=64,FF=2048,3 layers)
// Round 6 (resubmit): register+shfl topk, SSPLIT=7 mscore, 2-stage meanv,
// fused comb+scatter, merged weight-split launches, BN=128 everywhere.
// ---------------------------------------------------------------------------

#define SQ 1024
#define DM 512
#define NH 8
#define DH 64
#define DFF 2048
#define NTOP 35
#define ROWS 8192            // B*S
#define QKVD 1536            // fused Q|K|V row stride
#define EPSF 1e-5f
#define KSPLIT 8             // attention key splits
#define SSPLIT 7             // mscore sample splits (5 samples each)

typedef __attribute__((ext_vector_type(8))) short bf16x8;
typedef __attribute__((ext_vector_type(4))) float f32x4;

__device__ __forceinline__ void gload_lds16(const void* g, void* l) {
    __builtin_amdgcn_global_load_lds((const __attribute__((address_space(1))) void*)g,
                                     (__attribute__((address_space(3))) void*)l, 16, 0, 0);
}

__device__ inline float gelu_f(float v) {
    return 0.5f * v * (1.0f + erff(v * 0.7071067811865476f));
}

__device__ __forceinline__ void split_hl(float v, __hip_bfloat16& h, __hip_bfloat16& l) {
    h = __float2bfloat16(v);
    l = __float2bfloat16(v - __bfloat162float(h));
}

// ---------------- Threefry-2x32 (exact JAX PRNG) ---------------------------
__device__ inline void tf_round(uint32_t& x0, uint32_t& x1, int r) {
    x0 += x1;
    x1 = (x1 << r) | (x1 >> (32 - r));
    x1 ^= x0;
}
__device__ inline uint2 tf2x32(uint32_t k0, uint32_t k1, uint32_t x0, uint32_t x1) {
    uint32_t ks2 = k0 ^ k1 ^ 0x1BD11BDAu;
    x0 += k0; x1 += k1;
    tf_round(x0,x1,13); tf_round(x0,x1,15); tf_round(x0,x1,26); tf_round(x0,x1,6);
    x0 += k1; x1 += ks2 + 1u;
    tf_round(x0,x1,17); tf_round(x0,x1,29); tf_round(x0,x1,16); tf_round(x0,x1,24);
    x0 += ks2; x1 += k0 + 2u;
    tf_round(x0,x1,13); tf_round(x0,x1,15); tf_round(x0,x1,26); tf_round(x0,x1,6);
    x0 += k0; x1 += k1 + 3u;
    tf_round(x0,x1,17); tf_round(x0,x1,29); tf_round(x0,x1,16); tf_round(x0,x1,24);
    x0 += k1; x1 += ks2 + 4u;
    tf_round(x0,x1,13); tf_round(x0,x1,15); tf_round(x0,x1,26); tf_round(x0,x1,6);
    x0 += ks2; x1 += k0 + 5u;
    return make_uint2(x0, x1);
}

__global__ void idx_kernel(int lyr, int* __restrict__ idx) {
    int p = blockIdx.x * 256 + threadIdx.x;
    if (p >= SQ * NTOP) return;
    uint2 fk = tf2x32(0u, 42u, 0u, (uint32_t)lyr);
    uint2 a = tf2x32(fk.x, fk.y, 0u, 2u);
    uint2 bb = tf2x32(fk.x, fk.y, 1u, 3u);
    uint32_t k20 = a.y, k21 = bb.y;
    const int half = (SQ * NTOP) / 2;  // 17920
    uint32_t bits;
    if (p < half) bits = tf2x32(k20, k21, (uint32_t)p, (uint32_t)(half + p)).x;
    else          bits = tf2x32(k20, k21, (uint32_t)(p - half), (uint32_t)p).y;
    idx[p] = (int)(bits & 1023u);
}

// ------- conv1d token embedding + positional embedding (+fused split) ------
__global__ __launch_bounds__(256) void embed_kernel(const float* __restrict__ xe,
                                                    const float* __restrict__ tk,
                                                    float* __restrict__ X,
                                                    __hip_bfloat16* __restrict__ Xh,
                                                    __hip_bfloat16* __restrict__ Xl) {
    int row = blockIdx.x;            // b*1024+s
    int b = row >> 10, s = row & 1023;
    __shared__ float xv[9];
    int t = threadIdx.x;
    if (t < 9) {
        int w = t / 3, c = t % 3;
        int tt = s + w;
        int r = (tt == 0) ? 1023 : (tt <= 1024 ? tt - 1 : 0);
        xv[t] = xe[((size_t)b * SQ + r) * 3 + c];
    }
    __syncthreads();
    const float cdiv = 0.017988946039015984f;  // ln(10000)/512
    for (int d = t; d < DM; d += 256) {
        float acc = 0.f;
        #pragma unroll
        for (int wi = 0; wi < 9; ++wi) acc += xv[wi] * tk[wi * DM + d];
        int j2 = (d >> 1) * 2;
        float div = expf(-cdiv * (float)j2);
        float ang = (float)s * div;
        float pe = (d & 1) ? cosf(ang) : sinf(ang);
        float v = acc + pe;
        size_t o = (size_t)row * DM + d;
        X[o] = v;
        __hip_bfloat16 hb, lb; split_hl(v, hb, lb);
        Xh[o] = hb; Xl[o] = lb;
    }
}

// ------- merged weight split A: Wq|Wk|Wv -> WhA/WlA, Wo -> WhB/WlB, bias ---
__global__ __launch_bounds__(256) void wsplitA_kernel(
    const float* __restrict__ Wq, const float* __restrict__ Wk,
    const float* __restrict__ Wv, const float* __restrict__ Wo,
    const float* __restrict__ bq, const float* __restrict__ bk,
    const float* __restrict__ bv,
    __hip_bfloat16* __restrict__ ha, __hip_bfloat16* __restrict__ la,
    __hip_bfloat16* __restrict__ hb, __hip_bfloat16* __restrict__ lb,
    float* __restrict__ biasC) {
    int t = threadIdx.x;
    if (blockIdx.x == 1024) {   // bias concat block
        #pragma unroll
        for (int r = 0; r < 6; ++r) {
            int i = r * 256 + t;
            biasC[i] = (i < 512) ? bq[i] : (i < 1024) ? bk[i - 512] : bv[i - 1024];
        }
        return;
    }
    int i = blockIdx.x * 256 + t;          // 0..262143 float4
    int seg = i >> 16, local = i & 65535;
    const float* srcs[4] = {Wq, Wk, Wv, Wo};
    float4 v = reinterpret_cast<const float4*>(srcs[seg])[local];
    float vv[4] = {v.x, v.y, v.z, v.w};
    ushort hv[4], lv[4];
    #pragma unroll
    for (int j = 0; j < 4; ++j) {
        __hip_bfloat16 h_, l_; split_hl(vv[j], h_, l_);
        hv[j] = *reinterpret_cast<ushort*>(&h_);
        lv[j] = *reinterpret_cast<ushort*>(&l_);
    }
    ushort4 hq = make_ushort4(hv[0], hv[1], hv[2], hv[3]);
    ushort4 lq = make_ushort4(lv[0], lv[1], lv[2], lv[3]);
    if (seg < 3) {
        reinterpret_cast<ushort4*>(ha)[i] = hq;
        reinterpret_cast<ushort4*>(la)[i] = lq;
    } else {
        reinterpret_cast<ushort4*>(hb)[local] = hq;
        reinterpret_cast<ushort4*>(lb)[local] = lq;
    }
}

// ------- merged weight split B: c1w -> WhA/WlA, c2w -> WhB/WlB -------------
__global__ __launch_bounds__(256) void wsplitB_kernel(
    const float* __restrict__ c1w, const float* __restrict__ c2w,
    __hip_bfloat16* __restrict__ ha, __hip_bfloat16* __restrict__ la,
    __hip_bfloat16* __restrict__ hb, __hip_bfloat16* __restrict__ lb) {
    int i = blockIdx.x * 256 + threadIdx.x;  // 0..524287 float4
    int seg = i >> 18, local = i & 262143;
    const float* src = seg ? c2w : c1w;
    float4 v = reinterpret_cast<const float4*>(src)[local];
    float vv[4] = {v.x, v.y, v.z, v.w};
    ushort hv[4], lv[4];
    #pragma unroll
    for (int j = 0; j < 4; ++j) {
        __hip_bfloat16 h_, l_; split_hl(vv[j], h_, l_);
        hv[j] = *reinterpret_cast<ushort*>(&h_);
        lv[j] = *reinterpret_cast<ushort*>(&l_);
    }
    ushort4 hq = make_ushort4(hv[0], hv[1], hv[2], hv[3]);
    ushort4 lq = make_ushort4(lv[0], lv[1], lv[2], lv[3]);
    if (seg == 0) {
        reinterpret_cast<ushort4*>(ha)[local] = hq;
        reinterpret_cast<ushort4*>(la)[local] = lq;
    } else {
        reinterpret_cast<ushort4*>(hb)[local] = hq;
        reinterpret_cast<ushort4*>(lb)[local] = lq;
    }
}

// ---------------- split-bf16 MFMA GEMM (BK=64) -----------------------------
template<int BN_, int OUTMODE>
__global__ __launch_bounds__(256) void mfma_gemm(
    const __hip_bfloat16* __restrict__ Ah, const __hip_bfloat16* __restrict__ Al,
    const __hip_bfloat16* __restrict__ Wh, const __hip_bfloat16* __restrict__ Wl,
    const float* __restrict__ bias,
    float* __restrict__ C,
    __hip_bfloat16* __restrict__ Oh, __hip_bfloat16* __restrict__ Ol,
    int M, int N, int K) {
    constexpr int NI = BN_ / 32;           // b-frags per wave
    __shared__ __hip_bfloat16 As[128 * 64];
    __shared__ __hip_bfloat16 Bs[BN_ * 64];
    const int t = threadIdx.x;
    const int lane = t & 63, w = t >> 6;
    const int wm = w >> 1, wn = w & 1;
    const int bm = blockIdx.x * 128, bn = blockIdx.y * BN_;
    const int r15 = lane & 15, kc = lane >> 4;
    f32x4 acc[4][NI];
    #pragma unroll
    for (int mi = 0; mi < 4; ++mi)
        #pragma unroll
        for (int ni = 0; ni < NI; ++ni)
            acc[mi][ni] = (f32x4){0.f, 0.f, 0.f, 0.f};

    const int KT = 3 * K;
    for (int kp = 0; kp < KT; kp += 64) {
        int seg = (kp >= 2 * K) ? 2 : ((kp >= K) ? 1 : 0);
        int k0 = kp - seg * K;
        const __hip_bfloat16* Ab = (seg == 1) ? Al : Ah;
        const __hip_bfloat16* Bb = (seg == 2) ? Wl : Wh;
        #pragma unroll
        for (int i = 0; i < 4; ++i) {
            int slot = i * 256 + t;
            int row = slot >> 3, cp = slot & 7;
            int cl = cp ^ (row & 7);
            gload_lds16(Ab + (size_t)(bm + row) * K + k0 + cl * 8, As + slot * 8);
        }
        #pragma unroll
        for (int i = 0; i < BN_ / 32; ++i) {
            int slot = i * 256 + t;
            int row = slot >> 3, cp = slot & 7;
            int cl = cp ^ (row & 7);
            gload_lds16(Bb + (size_t)(bn + row) * K + k0 + cl * 8, Bs + slot * 8);
        }
        __syncthreads();
        #pragma unroll
        for (int kk = 0; kk < 2; ++kk) {
            bf16x8 a[4], b[NI];
            #pragma unroll
            for (int mi = 0; mi < 4; ++mi) {
                int row = wm * 64 + mi * 16 + r15;
                int sl = ((kk << 2) | kc) ^ (row & 7);
                a[mi] = *reinterpret_cast<const bf16x8*>(As + row * 64 + sl * 8);
            }
            #pragma unroll
            for (int ni = 0; ni < NI; ++ni) {
                int row = wn * (BN_ / 2) + ni * 16 + r15;
                int sl = ((kk << 2) | kc) ^ (row & 7);
                b[ni] = *reinterpret_cast<const bf16x8*>(Bs + row * 64 + sl * 8);
            }
            #pragma unroll
            for (int mi = 0; mi < 4; ++mi)
                #pragma unroll
                for (int ni = 0; ni < NI; ++ni)
                    acc[mi][ni] = __builtin_amdgcn_mfma_f32_16x16x32_bf16(a[mi], b[ni], acc[mi][ni], 0, 0, 0);
        }
        __syncthreads();
    }

    const int rq = lane >> 4;
    #pragma unroll
    for (int mi = 0; mi < 4; ++mi) {
        #pragma unroll
        for (int ni = 0; ni < NI; ++ni) {
            int n = bn + wn * (BN_ / 2) + ni * 16 + r15;
            float bz = bias[n];
            #pragma unroll
            for (int r = 0; r < 4; ++r) {
                int m = bm + wm * 64 + mi * 16 + rq * 4 + r;
                float v = acc[mi][ni][r] + bz;
                if constexpr (OUTMODE == 0) {
                    C[(size_t)m * N + n] = v;
                } else {
                    float g = gelu_f(v);
                    __hip_bfloat16 hb, lb; split_hl(g, hb, lb);
                    Oh[(size_t)m * N + n] = hb;
                    Ol[(size_t)m * N + n] = lb;
                }
            }
        }
    }
}

// ------- sparsity measure partials: sample-chunked gather (5 each) ---------
__global__ __launch_bounds__(128) void mscore_part(const float* __restrict__ QKV,
                                                   const int* __restrict__ idx,
                                                   float* __restrict__ MX,
                                                   float* __restrict__ SM) {
    int bh = blockIdx.x;                       // 64
    int l = blockIdx.y * 128 + threadIdx.x;    // 0..1023
    int sc = blockIdx.z;                       // 0..6
    int b = bh >> 3, h = bh & 7;
    const float4* q = reinterpret_cast<const float4*>(QKV + ((size_t)(b * SQ + l)) * QKVD + h * DH);
    float4 qr[16];
    #pragma unroll
    for (int i = 0; i < 16; ++i) qr[i] = q[i];
    int s0 = sc * 5;
    float mx = -INFINITY, sm = 0.f;
    #pragma unroll
    for (int s = s0; s < s0 + 5; ++s) {
        int ki = idx[l * NTOP + s];
        const float4* kr = reinterpret_cast<const float4*>(QKV + ((size_t)(b * SQ + ki)) * QKVD + DM + h * DH);
        float d = 0.f;
        #pragma unroll
        for (int i = 0; i < 16; ++i) {
            float4 kv = kr[i];
            d += qr[i].x * kv.x + qr[i].y * kv.y + qr[i].z * kv.z + qr[i].w * kv.w;
        }
        mx = fmaxf(mx, d);
        sm += d;
    }
    size_t o = ((size_t)(bh * SSPLIT + sc) << 10) + l;
    MX[o] = mx; SM[o] = sm;
}

// --------- top-35: register values + wave shfl argmax ----------------------
__global__ __launch_bounds__(256) void topk_kernel(const float* __restrict__ MX,
                                                   const float* __restrict__ SM,
                                                   int* __restrict__ Mtop) {
    int bh = blockIdx.x;
    int t = threadIdx.x, w = t >> 6, lane = t & 63;
    float v[4];
    #pragma unroll
    for (int j = 0; j < 4; ++j) {
        int i = j * 256 + t;
        float mx = -INFINITY, sm = 0.f;
        #pragma unroll
        for (int sc = 0; sc < SSPLIT; ++sc) {
            size_t o = ((size_t)(bh * SSPLIT + sc) << 10) + i;
            mx = fmaxf(mx, MX[o]);
            sm += SM[o];
        }
        v[j] = mx - sm * (1.0f / (float)SQ);
    }
    __shared__ float swv[4];
    __shared__ int swi[4];
    __shared__ int winner;
    for (int u = 0; u < NTOP; ++u) {
        float bv = v[0]; int bj = 0;
        #pragma unroll
        for (int j = 1; j < 4; ++j)
            if (v[j] > bv) { bv = v[j]; bj = j; }
        int bi = bj * 256 + t;
        #pragma unroll
        for (int off = 32; off; off >>= 1) {
            float ov = __shfl_xor(bv, off);
            int oi = __shfl_xor(bi, off);
            if (ov > bv || (ov == bv && oi < bi)) { bv = ov; bi = oi; }
        }
        if (lane == 0) { swv[w] = bv; swi[w] = bi; }
        __syncthreads();
        if (t == 0) {
            float gv = swv[0]; int gi = swi[0];
            #pragma unroll
            for (int k = 1; k < 4; ++k)
                if (swv[k] > gv || (swv[k] == gv && swi[k] < gi)) { gv = swv[k]; gi = swi[k]; }
            Mtop[bh * NTOP + u] = gi;
            winner = gi;
        }
        __syncthreads();
        int wi = winner;
        if ((wi & 255) == t) v[wi >> 8] = -INFINITY;
    }
}

// ------ split-K flash attention partials: 8 splits x 64 bh -----------------
__global__ __launch_bounds__(512) void attn_part(const float* __restrict__ QKV,
                                                 const int* __restrict__ Mtop,
                                                 float* __restrict__ PACC,
                                                 float* __restrict__ PM,
                                                 float* __restrict__ PL) {
    __shared__ float Qs[NTOP][68];
    __shared__ float Kt[64][68];
    __shared__ float Vt[64][68];
    __shared__ float St[NTOP][64];
    __shared__ float mS[NTOP], lS[NTOP], fS[NTOP];
    __shared__ int qidx[NTOP];
    int bh = blockIdx.x, ks = blockIdx.y;
    int b = bh >> 3, h = bh & 7;
    int t = threadIdx.x, w = t >> 6, lane = t & 63;
    if (t < NTOP) { qidx[t] = Mtop[bh * NTOP + t]; mS[t] = -INFINITY; lS[t] = 0.f; }
    __syncthreads();
    for (int u = w; u < NTOP; u += 8)
        Qs[u][lane] = QKV[((size_t)(b * SQ + qidx[u])) * QKVD + h * DH + lane];
    float a_acc[5] = {0.f, 0.f, 0.f, 0.f, 0.f};
    __syncthreads();
    for (int tk = ks * 2; tk < ks * 2 + 2; ++tk) {
        #pragma unroll
        for (int i = 0; i < 2; ++i) {
            int idx4 = i * 512 + t;            // 0..1023
            int kr = idx4 >> 4, c4 = (idx4 & 15) << 2;
            const float* kp = QKV + ((size_t)(b * SQ + tk * 64 + kr)) * QKVD + DM + h * DH + c4;
            *reinterpret_cast<float4*>(&Kt[kr][c4]) = *reinterpret_cast<const float4*>(kp);
            *reinterpret_cast<float4*>(&Vt[kr][c4]) = *reinterpret_cast<const float4*>(kp + DM);
        }
        __syncthreads();
        float sv[5] = {0.f, 0.f, 0.f, 0.f, 0.f};
        #pragma unroll
        for (int d4 = 0; d4 < 16; ++d4) {
            float4 kv = *reinterpret_cast<const float4*>(&Kt[lane][d4 << 2]);
            #pragma unroll
            for (int j = 0; j < 5; ++j) {
                int u = w + 8 * j;
                if (u < NTOP) {
                    float4 qv = *reinterpret_cast<const float4*>(&Qs[u][d4 << 2]);
                    sv[j] += qv.x * kv.x + qv.y * kv.y + qv.z * kv.z + qv.w * kv.w;
                }
            }
        }
        #pragma unroll
        for (int j = 0; j < 5; ++j) {
            int u = w + 8 * j;
            if (u < NTOP) {
                float s = sv[j] * 0.125f;
                float mx = s;
                #pragma unroll
                for (int off = 32; off; off >>= 1) mx = fmaxf(mx, __shfl_xor(mx, off));
                float m_old = mS[u];
                float m_new = fmaxf(m_old, mx);
                float e = expf(s - m_new);
                float sum = e;
                #pragma unroll
                for (int off = 32; off; off >>= 1) sum += __shfl_xor(sum, off);
                St[u][lane] = e;
                if (lane == 0) {
                    float f = expf(m_old - m_new);
                    fS[u] = f;
                    lS[u] = lS[u] * f + sum;
                    mS[u] = m_new;
                }
            }
        }
        __syncthreads();
        #pragma unroll
        for (int j = 0; j < 5; ++j) {
            int u = w + 8 * j;
            if (u < NTOP) {
                float acc = a_acc[j] * fS[u];
                for (int k = 0; k < 64; ++k)
                    acc += St[u][k] * Vt[k][lane];
                a_acc[j] = acc;
            }
        }
        __syncthreads();
    }
    #pragma unroll
    for (int j = 0; j < 5; ++j) {
        int u = w + 8 * j;
        if (u < NTOP) {
            PACC[(((size_t)bh * KSPLIT + ks) * NTOP + u) * DH + lane] = a_acc[j];
            if (lane == 0) {
                PM[((size_t)bh * KSPLIT + ks) * NTOP + u] = mS[u];
                PL[((size_t)bh * KSPLIT + ks) * NTOP + u] = lS[u];
            }
        }
    }
}

// ------- combine attention partials + scatter into context (bf16 h/l) ------
__global__ __launch_bounds__(512) void attn_comb(const float* __restrict__ PACC,
                                                 const float* __restrict__ PM,
                                                 const float* __restrict__ PL,
                                                 const int* __restrict__ Mtop,
                                                 __hip_bfloat16* __restrict__ ch,
                                                 __hip_bfloat16* __restrict__ cl) {
    int bh = blockIdx.x;
    int b = bh >> 3, h = bh & 7;
    int t = threadIdx.x, w = t >> 6, lane = t & 63;
    #pragma unroll
    for (int j = 0; j < 5; ++j) {
        int u = w + 8 * j;
        if (u < NTOP) {
            float M = -INFINITY;
            #pragma unroll
            for (int i = 0; i < KSPLIT; ++i)
                M = fmaxf(M, PM[((size_t)bh * KSPLIT + i) * NTOP + u]);
            float lsum = 0.f, acc = 0.f;
            #pragma unroll
            for (int i = 0; i < KSPLIT; ++i) {
                float f = expf(PM[((size_t)bh * KSPLIT + i) * NTOP + u] - M);
                lsum += f * PL[((size_t)bh * KSPLIT + i) * NTOP + u];
                acc += f * PACC[(((size_t)bh * KSPLIT + i) * NTOP + u) * DH + lane];
            }
            float v = acc / lsum;
            int l = Mtop[bh * NTOP + u];
            size_t o = ((size_t)(b * SQ + l)) * DM + h * DH + lane;
            __hip_bfloat16 hb, lb; split_hl(v, hb, lb);
            ch[o] = hb; cl[o] = lb;
        }
    }
}

// ---------------- V mean: two-stage ----------------------------------------
__global__ __launch_bounds__(256) void meanv_part(const float* __restrict__ QKV,
                                                  float* __restrict__ part) {
    int bh = blockIdx.x, sp = blockIdx.y;   // 64 x 8
    int t = threadIdx.x;
    int b = bh >> 3, h = bh & 7;
    int dh = t & 63, chunk = t >> 6;        // 4 chunks x 32 rows
    int s0 = sp * 128 + chunk * 32;
    float acc = 0.f;
    for (int s = s0; s < s0 + 32; ++s)
        acc += QKV[((size_t)(b * SQ + s)) * QKVD + 2 * DM + h * DH + dh];
    __shared__ float red[256];
    red[t] = acc; __syncthreads();
    if (t < 64)
        part[((size_t)bh * 8 + sp) * DH + dh] =
            red[t] + red[64 + t] + red[128 + t] + red[192 + t];
}

__global__ void meanv_comb(const float* __restrict__ part, float* __restrict__ meanV) {
    int bh = blockIdx.x;
    int t = threadIdx.x;  // 64
    float s = 0.f;
    #pragma unroll
    for (int i = 0; i < 8; ++i) s += part[((size_t)bh * 8 + i) * DH + t];
    meanV[bh * DH + t] = s * (1.0f / (float)SQ);
}

// ------- build context directly as bf16 hi/lo: broadcast meanV -------------
__global__ void ctxfill2_kernel(const float* __restrict__ meanV,
                                __hip_bfloat16* __restrict__ ch,
                                __hip_bfloat16* __restrict__ cl) {
    int n = blockIdx.x * 256 + threadIdx.x;   // 0 .. 4194303
    int d = n & 511;
    int row = n >> 9;
    int b = row >> 10;
    float v = meanV[((b << 3) + (d >> 6)) * DH + (d & 63)];
    __hip_bfloat16 hb, lb; split_hl(v, hb, lb);
    ch[n] = hb; cl[n] = lb;
}

// ---------------- residual add + LayerNorm (+fused split) ------------------
__global__ __launch_bounds__(256) void add_ln_kernel(const float* __restrict__ Av,
                                                     const float* __restrict__ Bv,
                                                     const float* __restrict__ g,
                                                     const float* __restrict__ be,
                                                     float* __restrict__ out,
                                                     __hip_bfloat16* __restrict__ oh,
                                                     __hip_bfloat16* __restrict__ ol) {
    int row = blockIdx.x;
    int t = threadIdx.x;
    size_t base = (size_t)row * DM;
    float v0 = Av[base + t] + Bv[base + t];
    float v1 = Av[base + 256 + t] + Bv[base + 256 + t];
    __shared__ float r1[256], r2[256];
    r1[t] = v0 + v1; r2[t] = v0 * v0 + v1 * v1;
    __syncthreads();
    for (int s = 128; s > 0; s >>= 1) {
        if (t < s) { r1[t] += r1[t + s]; r2[t] += r2[t + s]; }
        __syncthreads();
    }
    float mu = r1[0] * (1.0f / (float)DM);
    float var = r2[0] * (1.0f / (float)DM) - mu * mu;
    float rs = rsqrtf(var + EPSF);
    float o0 = (v0 - mu) * rs * g[t] + be[t];
    float o1 = (v1 - mu) * rs * g[t + 256] + be[t + 256];
    out[base + t] = o0;
    out[base + 256 + t] = o1;
    __hip_bfloat16 hb, lb;
    split_hl(o0, hb, lb); oh[base + t] = hb; ol[base + t] = lb;
    split_hl(o1, hb, lb); oh[base + 256 + t] = hb; ol[base + 256 + t] = lb;
}

// ---------------- final LN + GELU + mask -----------------------------------
__global__ __launch_bounds__(256) void final_kernel(const float* __restrict__ X,
                                                    const float* __restrict__ g,
                                                    const float* __restrict__ be,
                                                    const float* __restrict__ mark,
                                                    float* __restrict__ act) {
    int row = blockIdx.x;
    int t = threadIdx.x;
    size_t base = (size_t)row * DM;
    float v0 = X[base + t];
    float v1 = X[base + 256 + t];
    __shared__ float r1[256], r2[256];
    r1[t] = v0 + v1; r2[t] = v0 * v0 + v1 * v1;
    __syncthreads();
    for (int s = 128; s > 0; s >>= 1) {
        if (t < s) { r1[t] += r1[t + s]; r2[t] += r2[t + s]; }
        __syncthreads();
    }
    float mu = r1[0] * (1.0f / (float)DM);
    float var = r2[0] * (1.0f / (float)DM) - mu * mu;
    float rs = rsqrtf(var + EPSF);
    float mk = mark[row];
    float a0 = (v0 - mu) * rs * g[t] + be[t];
    float a1 = (v1 - mu) * rs * g[t + 256] + be[t + 256];
    act[base + t] = gelu_f(a0) * mk;
    act[base + 256 + t] = gelu_f(a1) * mk;
}

// ---------------- final projection: two-stage ------------------------------
__global__ __launch_bounds__(256) void proj1_kernel(const float* __restrict__ act,
                                                    const float* __restrict__ pw,
                                                    float* __restrict__ part) {
    int bc = blockIdx.x;      // 40
    int sg = blockIdx.y;      // 16
    int b = bc / 5, c = bc % 5;
    const float4* a = reinterpret_cast<const float4*>(act + (size_t)b * (SQ * DM) + sg * 32768);
    const float4* w = reinterpret_cast<const float4*>(pw + (size_t)c * (SQ * DM) + sg * 32768);
    float s = 0.f;
    for (int i = threadIdx.x; i < 8192; i += 256) {
        float4 av = a[i], wv = w[i];
        s += av.x * wv.x + av.y * wv.y + av.z * wv.z + av.w * wv.w;
    }
    __shared__ float red[256];
    red[threadIdx.x] = s; __syncthreads();
    for (int sft = 128; sft > 0; sft >>= 1) {
        if (threadIdx.x < sft) red[threadIdx.x] += red[threadIdx.x + sft];
        __syncthreads();
    }
    if (threadIdx.x == 0) part[bc * 16 + sg] = red[0];
}

__global__ void proj2_kernel(const float* __restrict__ part, const float* __restrict__ pb,
                             float* __restrict__ out) {
    int t = threadIdx.x;  // 64
    if (t < 40) {
        float s = 0.f;
        #pragma unroll
        for (int i = 0; i < 16; ++i) s += part[t * 16 + i];
        out[t] = s + pb[t % 5];
    }
}

// ---------------------------------------------------------------------------
extern "C" void kernel_launch(void* const* d_in, const int* in_sizes, int n_in,
                              void* d_out, int out_size, void* d_ws, size_t ws_size,
                              hipStream_t stream) {
    (void)in_sizes; (void)n_in; (void)out_size; (void)ws_size;

    const float* x_enc      = (const float*)d_in[0];
    const float* x_mark_enc = (const float*)d_in[1];
    const float* token_k    = (const float*)d_in[2];
    const float* Wq = (const float*)d_in[3];
    const float* bq = (const float*)d_in[4];
    const float* Wk = (const float*)d_in[5];
    const float* bk = (const float*)d_in[6];
    const float* Wv = (const float*)d_in[7];
    const float* bv = (const float*)d_in[8];
    const float* Wo = (const float*)d_in[9];
    const float* bo = (const float*)d_in[10];
    const float* c1w = (const float*)d_in[11];
    const float* c1b = (const float*)d_in[12];
    const float* c2w = (const float*)d_in[13];
    const float* c2b = (const float*)d_in[14];
    const float* g1 = (const float*)d_in[15];
    const float* b1 = (const float*)d_in[16];
    const float* g2 = (const float*)d_in[17];
    const float* b2 = (const float*)d_in[18];
    const float* gf = (const float*)d_in[19];
    const float* bf = (const float*)d_in[20];
    const float* proj_w = (const float*)d_in[21];
    const float* proj_b = (const float*)d_in[22];
    float* out = (float*)d_out;

    const size_t MB = 1024 * 1024;
    char* wsb = (char*)d_ws;
    float* X    = (float*)(wsb);                  // 0..16
    float* QKVp = (float*)(wsb + 16 * MB);        // 16..64 (8192x1536 fp32)
    __hip_bfloat16* CTXh = (__hip_bfloat16*)(wsb + 16 * MB);  // 16..24
    __hip_bfloat16* CTXl = (__hip_bfloat16*)(wsb + 24 * MB);  // 24..32
    __hip_bfloat16* Yh   = (__hip_bfloat16*)(wsb);            // 0..32 (X+CTX dead)
    __hip_bfloat16* Yl   = (__hip_bfloat16*)(wsb + 32 * MB);  // 32..64
    float* X1p  = (float*)(wsb + 64 * MB);        // 64..80
    float* NXp  = (float*)(wsb + 80 * MB);        // 80..96
    __hip_bfloat16* Xh  = (__hip_bfloat16*)(wsb + 96 * MB);   // 96..104
    __hip_bfloat16* Xl  = (__hip_bfloat16*)(wsb + 104 * MB);  // 104..112
    __hip_bfloat16* X1h = (__hip_bfloat16*)(wsb + 112 * MB);  // 112..120
    __hip_bfloat16* X1l = (__hip_bfloat16*)(wsb + 120 * MB);  // 120..128
    __hip_bfloat16* WhA = (__hip_bfloat16*)(wsb + 128 * MB);  // 128..130
    __hip_bfloat16* WlA = (__hip_bfloat16*)(wsb + 130 * MB);  // 130..132
    __hip_bfloat16* WhB = (__hip_bfloat16*)(wsb + 132 * MB);  // 132..134
    __hip_bfloat16* WlB = (__hip_bfloat16*)(wsb + 134 * MB);  // 134..136
    char* smal = wsb + 136 * MB;
    float* biasC  = (float*)(smal);                           // 8 KB
    int*   IDX    = (int*)(smal + 8 * 1024);                  // 160 KB
    int*   MTOP   = (int*)(smal + 168 * 1024);                // 16 KB
    float* MEANV  = (float*)(smal + 184 * 1024);              // 16 KB
    float* PART   = (float*)(smal + 200 * 1024);              // 8 KB
    float* MVPART = (float*)(smal + 208 * 1024);              // 128 KB + pad
    float* MX     = (float*)(smal + 384 * 1024);              // 1.75 MB
    float* SM     = (float*)(smal + 2176 * 1024);             // 1.75 MB
    float* PM     = (float*)(smal + 3968 * 1024);             // 96 KB
    float* PL     = (float*)(smal + 4064 * 1024);             // 96 KB
    float* PACC   = (float*)(smal + 4160 * 1024);             // 4.6 MB

    embed_kernel<<<ROWS, 256, 0, stream>>>(x_enc, token_k, X, Xh, Xl);

    for (int lyr = 0; lyr < 3; ++lyr) {
        const float* Wq_l = Wq + (size_t)lyr * DM * DM;
        const float* bq_l = bq + (size_t)lyr * DM;
        const float* Wk_l = Wk + (size_t)lyr * DM * DM;
        const float* bk_l = bk + (size_t)lyr * DM;
        const float* Wv_l = Wv + (size_t)lyr * DM * DM;
        const float* bv_l = bv + (size_t)lyr * DM;
        const float* Wo_l = Wo + (size_t)lyr * DM * DM;
        const float* bo_l = bo + (size_t)lyr * DM;
        const float* c1w_l = c1w + (size_t)lyr * DFF * DM;
        const float* c1b_l = c1b + (size_t)lyr * DFF;
        const float* c2w_l = c2w + (size_t)lyr * DM * DFF;
        const float* c2b_l = c2b + (size_t)lyr * DM;
        const float* g1_l = g1 + (size_t)lyr * DM;
        const float* b1_l = b1 + (size_t)lyr * DM;
        const float* g2_l = g2 + (size_t)lyr * DM;
        const float* b2_l = b2 + (size_t)lyr * DM;

        // ---- weight split A: QKV -> WhA, Wo -> WhB, bias concat ----
        wsplitA_kernel<<<1025, 256, 0, stream>>>(Wq_l, Wk_l, Wv_l, Wo_l,
                                                 bq_l, bk_l, bv_l,
                                                 WhA, WlA, WhB, WlB, biasC);
        // ---- fused QKV projection (N=1536) ----
        mfma_gemm<128, 0><<<dim3(ROWS / 128, QKVD / 128), 256, 0, stream>>>(
            Xh, Xl, WhA, WlA, biasC, QKVp, nullptr, nullptr, ROWS, QKVD, DM);

        // ---- ProbSparse attention ----
        idx_kernel<<<(SQ * NTOP + 255) / 256, 256, 0, stream>>>(lyr, IDX);
        mscore_part<<<dim3(64, 8, SSPLIT), 128, 0, stream>>>(QKVp, IDX, MX, SM);
        topk_kernel<<<64, 256, 0, stream>>>(MX, SM, MTOP);
        attn_part<<<dim3(64, KSPLIT), 512, 0, stream>>>(QKVp, MTOP, PACC, PM, PL);
        meanv_part<<<dim3(64, 8), 256, 0, stream>>>(QKVp, MVPART);
        meanv_comb<<<64, 64, 0, stream>>>(MVPART, MEANV);
        // QKV fp32 dead now; write context straight into its region as h/l
        ctxfill2_kernel<<<(ROWS * DM) / 256, 256, 0, stream>>>(MEANV, CTXh, CTXl);
        attn_comb<<<64, 512, 0, stream>>>(PACC, PM, PL, MTOP, CTXh, CTXl);

        // ---- attention out-projection (Wo in WhB) ----
        mfma_gemm<128, 0><<<dim3(ROWS / 128, DM / 128), 256, 0, stream>>>(
            CTXh, CTXl, WhB, WlB, bo_l, NXp, nullptr, nullptr, ROWS, DM, DM);
        add_ln_kernel<<<ROWS, 256, 0, stream>>>(X, NXp, g1_l, b1_l, X1p, X1h, X1l);

        // ---- weight split B: c1w -> WhA, c2w -> WhB ----
        wsplitB_kernel<<<2048, 256, 0, stream>>>(c1w_l, c2w_l, WhA, WlA, WhB, WlB);
        // ---- FFN (Y occupies 0..64MB where X/CTX/QKV are dead) ----
        mfma_gemm<128, 2><<<dim3(ROWS / 128, DFF / 128), 256, 0, stream>>>(
            X1h, X1l, WhA, WlA, c1b_l, nullptr, Yh, Yl, ROWS, DFF, DM);
        mfma_gemm<128, 0><<<dim3(ROWS / 128, DM / 128), 256, 0, stream>>>(
            Yh, Yl, WhB, WlB, c2b_l, NXp, nullptr, nullptr, ROWS, DM, DFF);
        add_ln_kernel<<<ROWS, 256, 0, stream>>>(X1p, NXp, g2_l, b2_l, X, Xh, Xl);
    }

    final_kernel<<<ROWS, 256, 0, stream>>>(X, gf, bf, x_mark_enc, (float*)QKVp);
    proj1_kernel<<<dim3(40, 16), 256, 0, stream>>>((float*)QKVp, proj_w, PART);
    proj2_kernel<<<1, 64, 0, stream>>>(PART, proj_b, out);
}

// Round 10
// 1372.648 us; speedup vs baseline: 1.2925x; 1.2925x over previous
//
#include <hip/hip_runtime.h>
#include <hip/hip_bf16.h>
#include <stdint.h>

// ---------------------------------------------------------------------------
// Informer encoder forward (B=8,S=1024,D=512,H=8,Dh=64,FF=2048,3 layers)
// Round 8 (3rd submit): revert BN=128 (out-proj/FFN2) and SSPLIT=7 regressions;
// 2-term split-bf16 on value path (QKV stays 3-term -> top-k selection exact).
// ---------------------------------------------------------------------------

#define SQ 1024
#define DM 512
#define NH 8
#define DH 64
#define DFF 2048
#define NTOP 35
#define ROWS 8192            // B*S
#define QKVD 1536            // fused Q|K|V row stride
#define EPSF 1e-5f
#define KSPLIT 8             // attention key splits
#define SSPLIT 4             // mscore sample splits (9/9/9/8)

typedef __attribute__((ext_vector_type(8))) short bf16x8;
typedef __attribute__((ext_vector_type(4))) float f32x4;

__device__ __forceinline__ void gload_lds16(const void* g, void* l) {
    __builtin_amdgcn_global_load_lds((const __attribute__((address_space(1))) void*)g,
                                     (__attribute__((address_space(3))) void*)l, 16, 0, 0);
}

__device__ inline float gelu_f(float v) {
    return 0.5f * v * (1.0f + erff(v * 0.7071067811865476f));
}

__device__ __forceinline__ void split_hl(float v, __hip_bfloat16& h, __hip_bfloat16& l) {
    h = __float2bfloat16(v);
    l = __float2bfloat16(v - __bfloat162float(h));
}

// ---------------- Threefry-2x32 (exact JAX PRNG) ---------------------------
__device__ inline void tf_round(uint32_t& x0, uint32_t& x1, int r) {
    x0 += x1;
    x1 = (x1 << r) | (x1 >> (32 - r));
    x1 ^= x0;
}
__device__ inline uint2 tf2x32(uint32_t k0, uint32_t k1, uint32_t x0, uint32_t x1) {
    uint32_t ks2 = k0 ^ k1 ^ 0x1BD11BDAu;
    x0 += k0; x1 += k1;
    tf_round(x0,x1,13); tf_round(x0,x1,15); tf_round(x0,x1,26); tf_round(x0,x1,6);
    x0 += k1; x1 += ks2 + 1u;
    tf_round(x0,x1,17); tf_round(x0,x1,29); tf_round(x0,x1,16); tf_round(x0,x1,24);
    x0 += ks2; x1 += k0 + 2u;
    tf_round(x0,x1,13); tf_round(x0,x1,15); tf_round(x0,x1,26); tf_round(x0,x1,6);
    x0 += k0; x1 += k1 + 3u;
    tf_round(x0,x1,17); tf_round(x0,x1,29); tf_round(x0,x1,16); tf_round(x0,x1,24);
    x0 += k1; x1 += ks2 + 4u;
    tf_round(x0,x1,13); tf_round(x0,x1,15); tf_round(x0,x1,26); tf_round(x0,x1,6);
    x0 += ks2; x1 += k0 + 5u;
    return make_uint2(x0, x1);
}

__global__ void idx_kernel(int lyr, int* __restrict__ idx) {
    int p = blockIdx.x * 256 + threadIdx.x;
    if (p >= SQ * NTOP) return;
    uint2 fk = tf2x32(0u, 42u, 0u, (uint32_t)lyr);
    uint2 a = tf2x32(fk.x, fk.y, 0u, 2u);
    uint2 bb = tf2x32(fk.x, fk.y, 1u, 3u);
    uint32_t k20 = a.y, k21 = bb.y;
    const int half = (SQ * NTOP) / 2;  // 17920
    uint32_t bits;
    if (p < half) bits = tf2x32(k20, k21, (uint32_t)p, (uint32_t)(half + p)).x;
    else          bits = tf2x32(k20, k21, (uint32_t)(p - half), (uint32_t)p).y;
    idx[p] = (int)(bits & 1023u);
}

// ------- conv1d token embedding + positional embedding (+fused split) ------
__global__ __launch_bounds__(256) void embed_kernel(const float* __restrict__ xe,
                                                    const float* __restrict__ tk,
                                                    float* __restrict__ X,
                                                    __hip_bfloat16* __restrict__ Xh,
                                                    __hip_bfloat16* __restrict__ Xl) {
    int row = blockIdx.x;            // b*1024+s
    int b = row >> 10, s = row & 1023;
    __shared__ float xv[9];
    int t = threadIdx.x;
    if (t < 9) {
        int w = t / 3, c = t % 3;
        int tt = s + w;
        int r = (tt == 0) ? 1023 : (tt <= 1024 ? tt - 1 : 0);
        xv[t] = xe[((size_t)b * SQ + r) * 3 + c];
    }
    __syncthreads();
    const float cdiv = 0.017988946039015984f;  // ln(10000)/512
    for (int d = t; d < DM; d += 256) {
        float acc = 0.f;
        #pragma unroll
        for (int wi = 0; wi < 9; ++wi) acc += xv[wi] * tk[wi * DM + d];
        int j2 = (d >> 1) * 2;
        float div = expf(-cdiv * (float)j2);
        float ang = (float)s * div;
        float pe = (d & 1) ? cosf(ang) : sinf(ang);
        float v = acc + pe;
        size_t o = (size_t)row * DM + d;
        X[o] = v;
        __hip_bfloat16 hb, lb; split_hl(v, hb, lb);
        Xh[o] = hb; Xl[o] = lb;
    }
}

// ------- merged weight split A: Wq|Wk|Wv -> WhA/WlA, Wo -> WhB/WlB, bias ---
__global__ __launch_bounds__(256) void wsplitA_kernel(
    const float* __restrict__ Wq, const float* __restrict__ Wk,
    const float* __restrict__ Wv, const float* __restrict__ Wo,
    const float* __restrict__ bq, const float* __restrict__ bk,
    const float* __restrict__ bv,
    __hip_bfloat16* __restrict__ ha, __hip_bfloat16* __restrict__ la,
    __hip_bfloat16* __restrict__ hb, __hip_bfloat16* __restrict__ lb,
    float* __restrict__ biasC) {
    int t = threadIdx.x;
    if (blockIdx.x == 1024) {   // bias concat block
        #pragma unroll
        for (int r = 0; r < 6; ++r) {
            int i = r * 256 + t;
            biasC[i] = (i < 512) ? bq[i] : (i < 1024) ? bk[i - 512] : bv[i - 1024];
        }
        return;
    }
    int i = blockIdx.x * 256 + t;          // 0..262143 float4
    int seg = i >> 16, local = i & 65535;
    const float* srcs[4] = {Wq, Wk, Wv, Wo};
    float4 v = reinterpret_cast<const float4*>(srcs[seg])[local];
    float vv[4] = {v.x, v.y, v.z, v.w};
    ushort hv[4], lv[4];
    #pragma unroll
    for (int j = 0; j < 4; ++j) {
        __hip_bfloat16 h_, l_; split_hl(vv[j], h_, l_);
        hv[j] = *reinterpret_cast<ushort*>(&h_);
        lv[j] = *reinterpret_cast<ushort*>(&l_);
    }
    ushort4 hq = make_ushort4(hv[0], hv[1], hv[2], hv[3]);
    ushort4 lq = make_ushort4(lv[0], lv[1], lv[2], lv[3]);
    if (seg < 3) {
        reinterpret_cast<ushort4*>(ha)[i] = hq;
        reinterpret_cast<ushort4*>(la)[i] = lq;
    } else {
        reinterpret_cast<ushort4*>(hb)[local] = hq;
        reinterpret_cast<ushort4*>(lb)[local] = lq;
    }
}

// ------- merged weight split B: c1w -> WhA/WlA, c2w -> WhB/WlB -------------
__global__ __launch_bounds__(256) void wsplitB_kernel(
    const float* __restrict__ c1w, const float* __restrict__ c2w,
    __hip_bfloat16* __restrict__ ha, __hip_bfloat16* __restrict__ la,
    __hip_bfloat16* __restrict__ hb, __hip_bfloat16* __restrict__ lb) {
    int i = blockIdx.x * 256 + threadIdx.x;  // 0..524287 float4
    int seg = i >> 18, local = i & 262143;
    const float* src = seg ? c2w : c1w;
    float4 v = reinterpret_cast<const float4*>(src)[local];
    float vv[4] = {v.x, v.y, v.z, v.w};
    ushort hv[4], lv[4];
    #pragma unroll
    for (int j = 0; j < 4; ++j) {
        __hip_bfloat16 h_, l_; split_hl(vv[j], h_, l_);
        hv[j] = *reinterpret_cast<ushort*>(&h_);
        lv[j] = *reinterpret_cast<ushort*>(&l_);
    }
    ushort4 hq = make_ushort4(hv[0], hv[1], hv[2], hv[3]);
    ushort4 lq = make_ushort4(lv[0], lv[1], lv[2], lv[3]);
    if (seg == 0) {
        reinterpret_cast<ushort4*>(ha)[local] = hq;
        reinterpret_cast<ushort4*>(la)[local] = lq;
    } else {
        reinterpret_cast<ushort4*>(hb)[local] = hq;
        reinterpret_cast<ushort4*>(lb)[local] = lq;
    }
}

// ---------------- split-bf16 MFMA GEMM (BK=64) -----------------------------
// NTERM=3: (Ah+Al)@Wh + Ah@Wl (fp32-level).  NTERM=2: (Ah+Al)@Wh (~2^-8 rel).
template<int BN_, int OUTMODE, int NTERM>
__global__ __launch_bounds__(256) void mfma_gemm(
    const __hip_bfloat16* __restrict__ Ah, const __hip_bfloat16* __restrict__ Al,
    const __hip_bfloat16* __restrict__ Wh, const __hip_bfloat16* __restrict__ Wl,
    const float* __restrict__ bias,
    float* __restrict__ C,
    __hip_bfloat16* __restrict__ Oh, __hip_bfloat16* __restrict__ Ol,
    int M, int N, int K) {
    constexpr int NI = BN_ / 32;           // b-frags per wave
    __shared__ __hip_bfloat16 As[128 * 64];
    __shared__ __hip_bfloat16 Bs[BN_ * 64];
    const int t = threadIdx.x;
    const int lane = t & 63, w = t >> 6;
    const int wm = w >> 1, wn = w & 1;
    const int bm = blockIdx.x * 128, bn = blockIdx.y * BN_;
    const int r15 = lane & 15, kc = lane >> 4;
    f32x4 acc[4][NI];
    #pragma unroll
    for (int mi = 0; mi < 4; ++mi)
        #pragma unroll
        for (int ni = 0; ni < NI; ++ni)
            acc[mi][ni] = (f32x4){0.f, 0.f, 0.f, 0.f};

    const int KT = NTERM * K;
    for (int kp = 0; kp < KT; kp += 64) {
        int seg = (NTERM == 3) ? ((kp >= 2 * K) ? 2 : ((kp >= K) ? 1 : 0))
                               : ((kp >= K) ? 1 : 0);
        int k0 = kp - seg * K;
        const __hip_bfloat16* Ab = (seg == 1) ? Al : Ah;
        const __hip_bfloat16* Bb = (NTERM == 3 && seg == 2) ? Wl : Wh;
        #pragma unroll
        for (int i = 0; i < 4; ++i) {
            int slot = i * 256 + t;
            int row = slot >> 3, cp = slot & 7;
            int cl = cp ^ (row & 7);
            gload_lds16(Ab + (size_t)(bm + row) * K + k0 + cl * 8, As + slot * 8);
        }
        #pragma unroll
        for (int i = 0; i < BN_ / 32; ++i) {
            int slot = i * 256 + t;
            int row = slot >> 3, cp = slot & 7;
            int cl = cp ^ (row & 7);
            gload_lds16(Bb + (size_t)(bn + row) * K + k0 + cl * 8, Bs + slot * 8);
        }
        __syncthreads();
        #pragma unroll
        for (int kk = 0; kk < 2; ++kk) {
            bf16x8 a[4], b[NI];
            #pragma unroll
            for (int mi = 0; mi < 4; ++mi) {
                int row = wm * 64 + mi * 16 + r15;
                int sl = ((kk << 2) | kc) ^ (row & 7);
                a[mi] = *reinterpret_cast<const bf16x8*>(As + row * 64 + sl * 8);
            }
            #pragma unroll
            for (int ni = 0; ni < NI; ++ni) {
                int row = wn * (BN_ / 2) + ni * 16 + r15;
                int sl = ((kk << 2) | kc) ^ (row & 7);
                b[ni] = *reinterpret_cast<const bf16x8*>(Bs + row * 64 + sl * 8);
            }
            #pragma unroll
            for (int mi = 0; mi < 4; ++mi)
                #pragma unroll
                for (int ni = 0; ni < NI; ++ni)
                    acc[mi][ni] = __builtin_amdgcn_mfma_f32_16x16x32_bf16(a[mi], b[ni], acc[mi][ni], 0, 0, 0);
        }
        __syncthreads();
    }

    const int rq = lane >> 4;
    #pragma unroll
    for (int mi = 0; mi < 4; ++mi) {
        #pragma unroll
        for (int ni = 0; ni < NI; ++ni) {
            int n = bn + wn * (BN_ / 2) + ni * 16 + r15;
            float bz = bias[n];
            #pragma unroll
            for (int r = 0; r < 4; ++r) {
                int m = bm + wm * 64 + mi * 16 + rq * 4 + r;
                float v = acc[mi][ni][r] + bz;
                if constexpr (OUTMODE == 0) {
                    C[(size_t)m * N + n] = v;
                } else {
                    float g = gelu_f(v);
                    __hip_bfloat16 hb, lb; split_hl(g, hb, lb);
                    Oh[(size_t)m * N + n] = hb;
                    Ol[(size_t)m * N + n] = lb;
                }
            }
        }
    }
}

// ------- sparsity measure partials: sample-chunked gather (9/9/9/8) --------
__global__ __launch_bounds__(128) void mscore_part(const float* __restrict__ QKV,
                                                   const int* __restrict__ idx,
                                                   float* __restrict__ MX,
                                                   float* __restrict__ SM) {
    int bh = blockIdx.x;                       // 64
    int l = blockIdx.y * 128 + threadIdx.x;    // 0..1023
    int sc = blockIdx.z;                       // 0..3
    int b = bh >> 3, h = bh & 7;
    const float4* q = reinterpret_cast<const float4*>(QKV + ((size_t)(b * SQ + l)) * QKVD + h * DH);
    float4 qr[16];
    #pragma unroll
    for (int i = 0; i < 16; ++i) qr[i] = q[i];
    int s0 = sc * 9;
    int s1 = (s0 + 9 < NTOP) ? s0 + 9 : NTOP;
    float mx = -INFINITY, sm = 0.f;
    for (int s = s0; s < s1; ++s) {
        int ki = idx[l * NTOP + s];
        const float4* kr = reinterpret_cast<const float4*>(QKV + ((size_t)(b * SQ + ki)) * QKVD + DM + h * DH);
        float d = 0.f;
        #pragma unroll
        for (int i = 0; i < 16; ++i) {
            float4 kv = kr[i];
            d += qr[i].x * kv.x + qr[i].y * kv.y + qr[i].z * kv.z + qr[i].w * kv.w;
        }
        mx = fmaxf(mx, d);
        sm += d;
    }
    size_t o = ((size_t)(bh * SSPLIT + sc) << 10) + l;
    MX[o] = mx; SM[o] = sm;
}

// --------- top-35: register values + wave shfl argmax ----------------------
__global__ __launch_bounds__(256) void topk_kernel(const float* __restrict__ MX,
                                                   const float* __restrict__ SM,
                                                   int* __restrict__ Mtop) {
    int bh = blockIdx.x;
    int t = threadIdx.x, w = t >> 6, lane = t & 63;
    float v[4];
    #pragma unroll
    for (int j = 0; j < 4; ++j) {
        int i = j * 256 + t;
        float mx = -INFINITY, sm = 0.f;
        #pragma unroll
        for (int sc = 0; sc < SSPLIT; ++sc) {
            size_t o = ((size_t)(bh * SSPLIT + sc) << 10) + i;
            mx = fmaxf(mx, MX[o]);
            sm += SM[o];
        }
        v[j] = mx - sm * (1.0f / (float)SQ);
    }
    __shared__ float swv[4];
    __shared__ int swi[4];
    __shared__ int winner;
    for (int u = 0; u < NTOP; ++u) {
        float bv = v[0]; int bj = 0;
        #pragma unroll
        for (int j = 1; j < 4; ++j)
            if (v[j] > bv) { bv = v[j]; bj = j; }
        int bi = bj * 256 + t;
        #pragma unroll
        for (int off = 32; off; off >>= 1) {
            float ov = __shfl_xor(bv, off);
            int oi = __shfl_xor(bi, off);
            if (ov > bv || (ov == bv && oi < bi)) { bv = ov; bi = oi; }
        }
        if (lane == 0) { swv[w] = bv; swi[w] = bi; }
        __syncthreads();
        if (t == 0) {
            float gv = swv[0]; int gi = swi[0];
            #pragma unroll
            for (int k = 1; k < 4; ++k)
                if (swv[k] > gv || (swv[k] == gv && swi[k] < gi)) { gv = swv[k]; gi = swi[k]; }
            Mtop[bh * NTOP + u] = gi;
            winner = gi;
        }
        __syncthreads();
        int wi = winner;
        if ((wi & 255) == t) v[wi >> 8] = -INFINITY;
    }
}

// ------ split-K flash attention partials: 8 splits x 64 bh -----------------
__global__ __launch_bounds__(512) void attn_part(const float* __restrict__ QKV,
                                                 const int* __restrict__ Mtop,
                                                 float* __restrict__ PACC,
                                                 float* __restrict__ PM,
                                                 float* __restrict__ PL) {
    __shared__ float Qs[NTOP][68];
    __shared__ float Kt[64][68];
    __shared__ float Vt[64][68];
    __shared__ float St[NTOP][64];
    __shared__ float mS[NTOP], lS[NTOP], fS[NTOP];
    __shared__ int qidx[NTOP];
    int bh = blockIdx.x, ks = blockIdx.y;
    int b = bh >> 3, h = bh & 7;
    int t = threadIdx.x, w = t >> 6, lane = t & 63;
    if (t < NTOP) { qidx[t] = Mtop[bh * NTOP + t]; mS[t] = -INFINITY; lS[t] = 0.f; }
    __syncthreads();
    for (int u = w; u < NTOP; u += 8)
        Qs[u][lane] = QKV[((size_t)(b * SQ + qidx[u])) * QKVD + h * DH + lane];
    float a_acc[5] = {0.f, 0.f, 0.f, 0.f, 0.f};
    __syncthreads();
    for (int tk = ks * 2; tk < ks * 2 + 2; ++tk) {
        #pragma unroll
        for (int i = 0; i < 2; ++i) {
            int idx4 = i * 512 + t;            // 0..1023
            int kr = idx4 >> 4, c4 = (idx4 & 15) << 2;
            const float* kp = QKV + ((size_t)(b * SQ + tk * 64 + kr)) * QKVD + DM + h * DH + c4;
            *reinterpret_cast<float4*>(&Kt[kr][c4]) = *reinterpret_cast<const float4*>(kp);
            *reinterpret_cast<float4*>(&Vt[kr][c4]) = *reinterpret_cast<const float4*>(kp + DM);
        }
        __syncthreads();
        float sv[5] = {0.f, 0.f, 0.f, 0.f, 0.f};
        #pragma unroll
        for (int d4 = 0; d4 < 16; ++d4) {
            float4 kv = *reinterpret_cast<const float4*>(&Kt[lane][d4 << 2]);
            #pragma unroll
            for (int j = 0; j < 5; ++j) {
                int u = w + 8 * j;
                if (u < NTOP) {
                    float4 qv = *reinterpret_cast<const float4*>(&Qs[u][d4 << 2]);
                    sv[j] += qv.x * kv.x + qv.y * kv.y + qv.z * kv.z + qv.w * kv.w;
                }
            }
        }
        #pragma unroll
        for (int j = 0; j < 5; ++j) {
            int u = w + 8 * j;
            if (u < NTOP) {
                float s = sv[j] * 0.125f;
                float mx = s;
                #pragma unroll
                for (int off = 32; off; off >>= 1) mx = fmaxf(mx, __shfl_xor(mx, off));
                float m_old = mS[u];
                float m_new = fmaxf(m_old, mx);
                float e = expf(s - m_new);
                float sum = e;
                #pragma unroll
                for (int off = 32; off; off >>= 1) sum += __shfl_xor(sum, off);
                St[u][lane] = e;
                if (lane == 0) {
                    float f = expf(m_old - m_new);
                    fS[u] = f;
                    lS[u] = lS[u] * f + sum;
                    mS[u] = m_new;
                }
            }
        }
        __syncthreads();
        #pragma unroll
        for (int j = 0; j < 5; ++j) {
            int u = w + 8 * j;
            if (u < NTOP) {
                float acc = a_acc[j] * fS[u];
                for (int k = 0; k < 64; ++k)
                    acc += St[u][k] * Vt[k][lane];
                a_acc[j] = acc;
            }
        }
        __syncthreads();
    }
    #pragma unroll
    for (int j = 0; j < 5; ++j) {
        int u = w + 8 * j;
        if (u < NTOP) {
            PACC[(((size_t)bh * KSPLIT + ks) * NTOP + u) * DH + lane] = a_acc[j];
            if (lane == 0) {
                PM[((size_t)bh * KSPLIT + ks) * NTOP + u] = mS[u];
                PL[((size_t)bh * KSPLIT + ks) * NTOP + u] = lS[u];
            }
        }
    }
}

// ------- combine attention partials + scatter into context (bf16 h/l) ------
__global__ __launch_bounds__(512) void attn_comb(const float* __restrict__ PACC,
                                                 const float* __restrict__ PM,
                                                 const float* __restrict__ PL,
                                                 const int* __restrict__ Mtop,
                                                 __hip_bfloat16* __restrict__ ch,
                                                 __hip_bfloat16* __restrict__ cl) {
    int bh = blockIdx.x;
    int b = bh >> 3, h = bh & 7;
    int t = threadIdx.x, w = t >> 6, lane = t & 63;
    #pragma unroll
    for (int j = 0; j < 5; ++j) {
        int u = w + 8 * j;
        if (u < NTOP) {
            float M = -INFINITY;
            #pragma unroll
            for (int i = 0; i < KSPLIT; ++i)
                M = fmaxf(M, PM[((size_t)bh * KSPLIT + i) * NTOP + u]);
            float lsum = 0.f, acc = 0.f;
            #pragma unroll
            for (int i = 0; i < KSPLIT; ++i) {
                float f = expf(PM[((size_t)bh * KSPLIT + i) * NTOP + u] - M);
                lsum += f * PL[((size_t)bh * KSPLIT + i) * NTOP + u];
                acc += f * PACC[(((size_t)bh * KSPLIT + i) * NTOP + u) * DH + lane];
            }
            float v = acc / lsum;
            int l = Mtop[bh * NTOP + u];
            size_t o = ((size_t)(b * SQ + l)) * DM + h * DH + lane;
            __hip_bfloat16 hb, lb; split_hl(v, hb, lb);
            ch[o] = hb; cl[o] = lb;
        }
    }
}

// ---------------- V mean: two-stage ----------------------------------------
__global__ __launch_bounds__(256) void meanv_part(const float* __restrict__ QKV,
                                                  float* __restrict__ part) {
    int bh = blockIdx.x, sp = blockIdx.y;   // 64 x 8
    int t = threadIdx.x;
    int b = bh >> 3, h = bh & 7;
    int dh = t & 63, chunk = t >> 6;        // 4 chunks x 32 rows
    int s0 = sp * 128 + chunk * 32;
    float acc = 0.f;
    for (int s = s0; s < s0 + 32; ++s)
        acc += QKV[((size_t)(b * SQ + s)) * QKVD + 2 * DM + h * DH + dh];
    __shared__ float red[256];
    red[t] = acc; __syncthreads();
    if (t < 64)
        part[((size_t)bh * 8 + sp) * DH + dh] =
            red[t] + red[64 + t] + red[128 + t] + red[192 + t];
}

__global__ void meanv_comb(const float* __restrict__ part, float* __restrict__ meanV) {
    int bh = blockIdx.x;
    int t = threadIdx.x;  // 64
    float s = 0.f;
    #pragma unroll
    for (int i = 0; i < 8; ++i) s += part[((size_t)bh * 8 + i) * DH + t];
    meanV[bh * DH + t] = s * (1.0f / (float)SQ);
}

// ------- build context directly as bf16 hi/lo: broadcast meanV -------------
__global__ void ctxfill2_kernel(const float* __restrict__ meanV,
                                __hip_bfloat16* __restrict__ ch,
                                __hip_bfloat16* __restrict__ cl) {
    int n = blockIdx.x * 256 + threadIdx.x;   // 0 .. 4194303
    int d = n & 511;
    int row = n >> 9;
    int b = row >> 10;
    float v = meanV[((b << 3) + (d >> 6)) * DH + (d & 63)];
    __hip_bfloat16 hb, lb; split_hl(v, hb, lb);
    ch[n] = hb; cl[n] = lb;
}

// ---------------- residual add + LayerNorm (+fused split) ------------------
__global__ __launch_bounds__(256) void add_ln_kernel(const float* __restrict__ Av,
                                                     const float* __restrict__ Bv,
                                                     const float* __restrict__ g,
                                                     const float* __restrict__ be,
                                                     float* __restrict__ out,
                                                     __hip_bfloat16* __restrict__ oh,
                                                     __hip_bfloat16* __restrict__ ol) {
    int row = blockIdx.x;
    int t = threadIdx.x;
    size_t base = (size_t)row * DM;
    float v0 = Av[base + t] + Bv[base + t];
    float v1 = Av[base + 256 + t] + Bv[base + 256 + t];
    __shared__ float r1[256], r2[256];
    r1[t] = v0 + v1; r2[t] = v0 * v0 + v1 * v1;
    __syncthreads();
    for (int s = 128; s > 0; s >>= 1) {
        if (t < s) { r1[t] += r1[t + s]; r2[t] += r2[t + s]; }
        __syncthreads();
    }
    float mu = r1[0] * (1.0f / (float)DM);
    float var = r2[0] * (1.0f / (float)DM) - mu * mu;
    float rs = rsqrtf(var + EPSF);
    float o0 = (v0 - mu) * rs * g[t] + be[t];
    float o1 = (v1 - mu) * rs * g[t + 256] + be[t + 256];
    out[base + t] = o0;
    out[base + 256 + t] = o1;
    __hip_bfloat16 hb, lb;
    split_hl(o0, hb, lb); oh[base + t] = hb; ol[base + t] = lb;
    split_hl(o1, hb, lb); oh[base + 256 + t] = hb; ol[base + 256 + t] = lb;
}

// ---------------- final LN + GELU + mask -----------------------------------
__global__ __launch_bounds__(256) void final_kernel(const float* __restrict__ X,
                                                    const float* __restrict__ g,
                                                    const float* __restrict__ be,
                                                    const float* __restrict__ mark,
                                                    float* __restrict__ act) {
    int row = blockIdx.x;
    int t = threadIdx.x;
    size_t base = (size_t)row * DM;
    float v0 = X[base + t];
    float v1 = X[base + 256 + t];
    __shared__ float r1[256], r2[256];
    r1[t] = v0 + v1; r2[t] = v0 * v0 + v1 * v1;
    __syncthreads();
    for (int s = 128; s > 0; s >>= 1) {
        if (t < s) { r1[t] += r1[t + s]; r2[t] += r2[t + s]; }
        __syncthreads();
    }
    float mu = r1[0] * (1.0f / (float)DM);
    float var = r2[0] * (1.0f / (float)DM) - mu * mu;
    float rs = rsqrtf(var + EPSF);
    float mk = mark[row];
    float a0 = (v0 - mu) * rs * g[t] + be[t];
    float a1 = (v1 - mu) * rs * g[t + 256] + be[t + 256];
    act[base + t] = gelu_f(a0) * mk;
    act[base + 256 + t] = gelu_f(a1) * mk;
}

// ---------------- final projection: two-stage ------------------------------
__global__ __launch_bounds__(256) void proj1_kernel(const float* __restrict__ act,
                                                    const float* __restrict__ pw,
                                                    float* __restrict__ part) {
    int bc = blockIdx.x;      // 40
    int sg = blockIdx.y;      // 16
    int b = bc / 5, c = bc % 5;
    const float4* a = reinterpret_cast<const float4*>(act + (size_t)b * (SQ * DM) + sg * 32768);
    const float4* w = reinterpret_cast<const float4*>(pw + (size_t)c * (SQ * DM) + sg * 32768);
    float s = 0.f;
    for (int i = threadIdx.x; i < 8192; i += 256) {
        float4 av = a[i], wv = w[i];
        s += av.x * wv.x + av.y * wv.y + av.z * wv.z + av.w * wv.w;
    }
    __shared__ float red[256];
    red[threadIdx.x] = s; __syncthreads();
    for (int sft = 128; sft > 0; sft >>= 1) {
        if (threadIdx.x < sft) red[threadIdx.x] += red[threadIdx.x + sft];
        __syncthreads();
    }
    if (threadIdx.x == 0) part[bc * 16 + sg] = red[0];
}

__global__ void proj2_kernel(const float* __restrict__ part, const float* __restrict__ pb,
                             float* __restrict__ out) {
    int t = threadIdx.x;  // 64
    if (t < 40) {
        float s = 0.f;
        #pragma unroll
        for (int i = 0; i < 16; ++i) s += part[t * 16 + i];
        out[t] = s + pb[t % 5];
    }
}

// ---------------------------------------------------------------------------
extern "C" void kernel_launch(void* const* d_in, const int* in_sizes, int n_in,
                              void* d_out, int out_size, void* d_ws, size_t ws_size,
                              hipStream_t stream) {
    (void)in_sizes; (void)n_in; (void)out_size; (void)ws_size;

    const float* x_enc      = (const float*)d_in[0];
    const float* x_mark_enc = (const float*)d_in[1];
    const float* token_k    = (const float*)d_in[2];
    const float* Wq = (const float*)d_in[3];
    const float* bq = (const float*)d_in[4];
    const float* Wk = (const float*)d_in[5];
    const float* bk = (const float*)d_in[6];
    const float* Wv = (const float*)d_in[7];
    const float* bv = (const float*)d_in[8];
    const float* Wo = (const float*)d_in[9];
    const float* bo = (const float*)d_in[10];
    const float* c1w = (const float*)d_in[11];
    const float* c1b = (const float*)d_in[12];
    const float* c2w = (const float*)d_in[13];
    const float* c2b = (const float*)d_in[14];
    const float* g1 = (const float*)d_in[15];
    const float* b1 = (const float*)d_in[16];
    const float* g2 = (const float*)d_in[17];
    const float* b2 = (const float*)d_in[18];
    const float* gf = (const float*)d_in[19];
    const float* bf = (const float*)d_in[20];
    const float* proj_w = (const float*)d_in[21];
    const float* proj_b = (const float*)d_in[22];
    float* out = (float*)d_out;

    const size_t MB = 1024 * 1024;
    char* wsb = (char*)d_ws;
    float* X    = (float*)(wsb);                  // 0..16
    float* QKVp = (float*)(wsb + 16 * MB);        // 16..64 (8192x1536 fp32)
    __hip_bfloat16* CTXh = (__hip_bfloat16*)(wsb + 16 * MB);  // 16..24
    __hip_bfloat16* CTXl = (__hip_bfloat16*)(wsb + 24 * MB);  // 24..32
    __hip_bfloat16* Yh   = (__hip_bfloat16*)(wsb);            // 0..32 (X+CTX dead)
    __hip_bfloat16* Yl   = (__hip_bfloat16*)(wsb + 32 * MB);  // 32..64
    float* X1p  = (float*)(wsb + 64 * MB);        // 64..80
    float* NXp  = (float*)(wsb + 80 * MB);        // 80..96
    __hip_bfloat16* Xh  = (__hip_bfloat16*)(wsb + 96 * MB);   // 96..104
    __hip_bfloat16* Xl  = (__hip_bfloat16*)(wsb + 104 * MB);  // 104..112
    __hip_bfloat16* X1h = (__hip_bfloat16*)(wsb + 112 * MB);  // 112..120
    __hip_bfloat16* X1l = (__hip_bfloat16*)(wsb + 120 * MB);  // 120..128
    __hip_bfloat16* WhA = (__hip_bfloat16*)(wsb + 128 * MB);  // 128..130
    __hip_bfloat16* WlA = (__hip_bfloat16*)(wsb + 130 * MB);  // 130..132
    __hip_bfloat16* WhB = (__hip_bfloat16*)(wsb + 132 * MB);  // 132..134
    __hip_bfloat16* WlB = (__hip_bfloat16*)(wsb + 134 * MB);  // 134..136
    char* smal = wsb + 136 * MB;
    float* biasC  = (float*)(smal);                           // 8 KB
    int*   IDX    = (int*)(smal + 8 * 1024);                  // 160 KB
    int*   MTOP   = (int*)(smal + 168 * 1024);                // 16 KB
    float* MEANV  = (float*)(smal + 184 * 1024);              // 16 KB
    float* PART   = (float*)(smal + 200 * 1024);              // 8 KB
    float* MVPART = (float*)(smal + 208 * 1024);              // 128 KB + pad
    float* MX     = (float*)(smal + 384 * 1024);              // 1.75 MB
    float* SM     = (float*)(smal + 2176 * 1024);             // 1.75 MB
    float* PM     = (float*)(smal + 3968 * 1024);             // 96 KB
    float* PL     = (float*)(smal + 4064 * 1024);             // 96 KB
    float* PACC   = (float*)(smal + 4160 * 1024);             // 4.6 MB

    embed_kernel<<<ROWS, 256, 0, stream>>>(x_enc, token_k, X, Xh, Xl);

    for (int lyr = 0; lyr < 3; ++lyr) {
        const float* Wq_l = Wq + (size_t)lyr * DM * DM;
        const float* bq_l = bq + (size_t)lyr * DM;
        const float* Wk_l = Wk + (size_t)lyr * DM * DM;
        const float* bk_l = bk + (size_t)lyr * DM;
        const float* Wv_l = Wv + (size_t)lyr * DM * DM;
        const float* bv_l = bv + (size_t)lyr * DM;
        const float* Wo_l = Wo + (size_t)lyr * DM * DM;
        const float* bo_l = bo + (size_t)lyr * DM;
        const float* c1w_l = c1w + (size_t)lyr * DFF * DM;
        const float* c1b_l = c1b + (size_t)lyr * DFF;
        const float* c2w_l = c2w + (size_t)lyr * DM * DFF;
        const float* c2b_l = c2b + (size_t)lyr * DM;
        const float* g1_l = g1 + (size_t)lyr * DM;
        const float* b1_l = b1 + (size_t)lyr * DM;
        const float* g2_l = g2 + (size_t)lyr * DM;
        const float* b2_l = b2 + (size_t)lyr * DM;

        // ---- weight split A: QKV -> WhA, Wo -> WhB, bias concat ----
        wsplitA_kernel<<<1025, 256, 0, stream>>>(Wq_l, Wk_l, Wv_l, Wo_l,
                                                 bq_l, bk_l, bv_l,
                                                 WhA, WlA, WhB, WlB, biasC);
        // ---- fused QKV projection (N=1536), 3-term (selection-exact) ----
        mfma_gemm<128, 0, 3><<<dim3(ROWS / 128, QKVD / 128), 256, 0, stream>>>(
            Xh, Xl, WhA, WlA, biasC, QKVp, nullptr, nullptr, ROWS, QKVD, DM);

        // ---- ProbSparse attention ----
        idx_kernel<<<(SQ * NTOP + 255) / 256, 256, 0, stream>>>(lyr, IDX);
        mscore_part<<<dim3(64, 8, SSPLIT), 128, 0, stream>>>(QKVp, IDX, MX, SM);
        topk_kernel<<<64, 256, 0, stream>>>(MX, SM, MTOP);
        attn_part<<<dim3(64, KSPLIT), 512, 0, stream>>>(QKVp, MTOP, PACC, PM, PL);
        meanv_part<<<dim3(64, 8), 256, 0, stream>>>(QKVp, MVPART);
        meanv_comb<<<64, 64, 0, stream>>>(MVPART, MEANV);
        // QKV fp32 dead now; write context straight into its region as h/l
        ctxfill2_kernel<<<(ROWS * DM) / 256, 256, 0, stream>>>(MEANV, CTXh, CTXl);
        attn_comb<<<64, 512, 0, stream>>>(PACC, PM, PL, MTOP, CTXh, CTXl);

        // ---- attention out-projection (Wo in WhB), 2-term value path ----
        mfma_gemm<64, 0, 2><<<dim3(ROWS / 128, DM / 64), 256, 0, stream>>>(
            CTXh, CTXl, WhB, WlB, bo_l, NXp, nullptr, nullptr, ROWS, DM, DM);
        add_ln_kernel<<<ROWS, 256, 0, stream>>>(X, NXp, g1_l, b1_l, X1p, X1h, X1l);

        // ---- weight split B: c1w -> WhA, c2w -> WhB ----
        wsplitB_kernel<<<2048, 256, 0, stream>>>(c1w_l, c2w_l, WhA, WlA, WhB, WlB);
        // ---- FFN (Y occupies 0..64MB where X/CTX/QKV are dead), 2-term ----
        mfma_gemm<128, 2, 2><<<dim3(ROWS / 128, DFF / 128), 256, 0, stream>>>(
            X1h, X1l, WhA, WlA, c1b_l, nullptr, Yh, Yl, ROWS, DFF, DM);
        mfma_gemm<64, 0, 2><<<dim3(ROWS / 128, DM / 64), 256, 0, stream>>>(
            Yh, Yl, WhB, WlB, c2b_l, NXp, nullptr, nullptr, ROWS, DM, DFF);
        add_ln_kernel<<<ROWS, 256, 0, stream>>>(X1p, NXp, g2_l, b2_l, X, Xh, Xl);
    }

    final_kernel<<<ROWS, 256, 0, stream>>>(X, gf, bf, x_mark_enc, (float*)QKVp);
    proj1_kernel<<<dim3(40, 16), 256, 0, stream>>>((float*)QKVp, proj_w, PART);
    proj2_kernel<<<1, 64, 0, stream>>>(PART, proj_b, out);
}

// Round 11
// 1200.841 us; speedup vs baseline: 1.4775x; 1.1431x over previous
//
#include <hip/hip_runtime.h>
#include <hip/hip_bf16.h>
#include <stdint.h>

// ---------------------------------------------------------------------------
// Informer encoder forward (B=8,S=1024,D=512,H=8,Dh=64,FF=2048,3 layers)
// Round 11: wave-parallel mscore (16 lanes/row, 35 independent gathers,
// shfl reduce) replacing the register-heavy serial-gather version.
// Everything else frozen at the round-10 (1373 us) configuration.
// ---------------------------------------------------------------------------

#define SQ 1024
#define DM 512
#define NH 8
#define DH 64
#define DFF 2048
#define NTOP 35
#define ROWS 8192            // B*S
#define QKVD 1536            // fused Q|K|V row stride
#define EPSF 1e-5f
#define KSPLIT 8             // attention key splits

typedef __attribute__((ext_vector_type(8))) short bf16x8;
typedef __attribute__((ext_vector_type(4))) float f32x4;

__device__ __forceinline__ void gload_lds16(const void* g, void* l) {
    __builtin_amdgcn_global_load_lds((const __attribute__((address_space(1))) void*)g,
                                     (__attribute__((address_space(3))) void*)l, 16, 0, 0);
}

__device__ inline float gelu_f(float v) {
    return 0.5f * v * (1.0f + erff(v * 0.7071067811865476f));
}

__device__ __forceinline__ void split_hl(float v, __hip_bfloat16& h, __hip_bfloat16& l) {
    h = __float2bfloat16(v);
    l = __float2bfloat16(v - __bfloat162float(h));
}

// ---------------- Threefry-2x32 (exact JAX PRNG) ---------------------------
__device__ inline void tf_round(uint32_t& x0, uint32_t& x1, int r) {
    x0 += x1;
    x1 = (x1 << r) | (x1 >> (32 - r));
    x1 ^= x0;
}
__device__ inline uint2 tf2x32(uint32_t k0, uint32_t k1, uint32_t x0, uint32_t x1) {
    uint32_t ks2 = k0 ^ k1 ^ 0x1BD11BDAu;
    x0 += k0; x1 += k1;
    tf_round(x0,x1,13); tf_round(x0,x1,15); tf_round(x0,x1,26); tf_round(x0,x1,6);
    x0 += k1; x1 += ks2 + 1u;
    tf_round(x0,x1,17); tf_round(x0,x1,29); tf_round(x0,x1,16); tf_round(x0,x1,24);
    x0 += ks2; x1 += k0 + 2u;
    tf_round(x0,x1,13); tf_round(x0,x1,15); tf_round(x0,x1,26); tf_round(x0,x1,6);
    x0 += k0; x1 += k1 + 3u;
    tf_round(x0,x1,17); tf_round(x0,x1,29); tf_round(x0,x1,16); tf_round(x0,x1,24);
    x0 += k1; x1 += ks2 + 4u;
    tf_round(x0,x1,13); tf_round(x0,x1,15); tf_round(x0,x1,26); tf_round(x0,x1,6);
    x0 += ks2; x1 += k0 + 5u;
    return make_uint2(x0, x1);
}

__global__ void idx_kernel(int lyr, int* __restrict__ idx) {
    int p = blockIdx.x * 256 + threadIdx.x;
    if (p >= SQ * NTOP) return;
    uint2 fk = tf2x32(0u, 42u, 0u, (uint32_t)lyr);
    uint2 a = tf2x32(fk.x, fk.y, 0u, 2u);
    uint2 bb = tf2x32(fk.x, fk.y, 1u, 3u);
    uint32_t k20 = a.y, k21 = bb.y;
    const int half = (SQ * NTOP) / 2;  // 17920
    uint32_t bits;
    if (p < half) bits = tf2x32(k20, k21, (uint32_t)p, (uint32_t)(half + p)).x;
    else          bits = tf2x32(k20, k21, (uint32_t)(p - half), (uint32_t)p).y;
    idx[p] = (int)(bits & 1023u);
}

// ------- conv1d token embedding + positional embedding (+fused split) ------
__global__ __launch_bounds__(256) void embed_kernel(const float* __restrict__ xe,
                                                    const float* __restrict__ tk,
                                                    float* __restrict__ X,
                                                    __hip_bfloat16* __restrict__ Xh,
                                                    __hip_bfloat16* __restrict__ Xl) {
    int row = blockIdx.x;            // b*1024+s
    int b = row >> 10, s = row & 1023;
    __shared__ float xv[9];
    int t = threadIdx.x;
    if (t < 9) {
        int w = t / 3, c = t % 3;
        int tt = s + w;
        int r = (tt == 0) ? 1023 : (tt <= 1024 ? tt - 1 : 0);
        xv[t] = xe[((size_t)b * SQ + r) * 3 + c];
    }
    __syncthreads();
    const float cdiv = 0.017988946039015984f;  // ln(10000)/512
    for (int d = t; d < DM; d += 256) {
        float acc = 0.f;
        #pragma unroll
        for (int wi = 0; wi < 9; ++wi) acc += xv[wi] * tk[wi * DM + d];
        int j2 = (d >> 1) * 2;
        float div = expf(-cdiv * (float)j2);
        float ang = (float)s * div;
        float pe = (d & 1) ? cosf(ang) : sinf(ang);
        float v = acc + pe;
        size_t o = (size_t)row * DM + d;
        X[o] = v;
        __hip_bfloat16 hb, lb; split_hl(v, hb, lb);
        Xh[o] = hb; Xl[o] = lb;
    }
}

// ------- merged weight split A: Wq|Wk|Wv -> WhA/WlA, Wo -> WhB/WlB, bias ---
__global__ __launch_bounds__(256) void wsplitA_kernel(
    const float* __restrict__ Wq, const float* __restrict__ Wk,
    const float* __restrict__ Wv, const float* __restrict__ Wo,
    const float* __restrict__ bq, const float* __restrict__ bk,
    const float* __restrict__ bv,
    __hip_bfloat16* __restrict__ ha, __hip_bfloat16* __restrict__ la,
    __hip_bfloat16* __restrict__ hb, __hip_bfloat16* __restrict__ lb,
    float* __restrict__ biasC) {
    int t = threadIdx.x;
    if (blockIdx.x == 1024) {   // bias concat block
        #pragma unroll
        for (int r = 0; r < 6; ++r) {
            int i = r * 256 + t;
            biasC[i] = (i < 512) ? bq[i] : (i < 1024) ? bk[i - 512] : bv[i - 1024];
        }
        return;
    }
    int i = blockIdx.x * 256 + t;          // 0..262143 float4
    int seg = i >> 16, local = i & 65535;
    const float* srcs[4] = {Wq, Wk, Wv, Wo};
    float4 v = reinterpret_cast<const float4*>(srcs[seg])[local];
    float vv[4] = {v.x, v.y, v.z, v.w};
    ushort hv[4], lv[4];
    #pragma unroll
    for (int j = 0; j < 4; ++j) {
        __hip_bfloat16 h_, l_; split_hl(vv[j], h_, l_);
        hv[j] = *reinterpret_cast<ushort*>(&h_);
        lv[j] = *reinterpret_cast<ushort*>(&l_);
    }
    ushort4 hq = make_ushort4(hv[0], hv[1], hv[2], hv[3]);
    ushort4 lq = make_ushort4(lv[0], lv[1], lv[2], lv[3]);
    if (seg < 3) {
        reinterpret_cast<ushort4*>(ha)[i] = hq;
        reinterpret_cast<ushort4*>(la)[i] = lq;
    } else {
        reinterpret_cast<ushort4*>(hb)[local] = hq;
        reinterpret_cast<ushort4*>(lb)[local] = lq;
    }
}

// ------- merged weight split B: c1w -> WhA/WlA, c2w -> WhB/WlB -------------
__global__ __launch_bounds__(256) void wsplitB_kernel(
    const float* __restrict__ c1w, const float* __restrict__ c2w,
    __hip_bfloat16* __restrict__ ha, __hip_bfloat16* __restrict__ la,
    __hip_bfloat16* __restrict__ hb, __hip_bfloat16* __restrict__ lb) {
    int i = blockIdx.x * 256 + threadIdx.x;  // 0..524287 float4
    int seg = i >> 18, local = i & 262143;
    const float* src = seg ? c2w : c1w;
    float4 v = reinterpret_cast<const float4*>(src)[local];
    float vv[4] = {v.x, v.y, v.z, v.w};
    ushort hv[4], lv[4];
    #pragma unroll
    for (int j = 0; j < 4; ++j) {
        __hip_bfloat16 h_, l_; split_hl(vv[j], h_, l_);
        hv[j] = *reinterpret_cast<ushort*>(&h_);
        lv[j] = *reinterpret_cast<ushort*>(&l_);
    }
    ushort4 hq = make_ushort4(hv[0], hv[1], hv[2], hv[3]);
    ushort4 lq = make_ushort4(lv[0], lv[1], lv[2], lv[3]);
    if (seg == 0) {
        reinterpret_cast<ushort4*>(ha)[local] = hq;
        reinterpret_cast<ushort4*>(la)[local] = lq;
    } else {
        reinterpret_cast<ushort4*>(hb)[local] = hq;
        reinterpret_cast<ushort4*>(lb)[local] = lq;
    }
}

// ---------------- split-bf16 MFMA GEMM (BK=64) -----------------------------
// NTERM=3: (Ah+Al)@Wh + Ah@Wl (fp32-level).  NTERM=2: (Ah+Al)@Wh (~2^-8 rel).
template<int BN_, int OUTMODE, int NTERM>
__global__ __launch_bounds__(256) void mfma_gemm(
    const __hip_bfloat16* __restrict__ Ah, const __hip_bfloat16* __restrict__ Al,
    const __hip_bfloat16* __restrict__ Wh, const __hip_bfloat16* __restrict__ Wl,
    const float* __restrict__ bias,
    float* __restrict__ C,
    __hip_bfloat16* __restrict__ Oh, __hip_bfloat16* __restrict__ Ol,
    int M, int N, int K) {
    constexpr int NI = BN_ / 32;           // b-frags per wave
    __shared__ __hip_bfloat16 As[128 * 64];
    __shared__ __hip_bfloat16 Bs[BN_ * 64];
    const int t = threadIdx.x;
    const int lane = t & 63, w = t >> 6;
    const int wm = w >> 1, wn = w & 1;
    const int bm = blockIdx.x * 128, bn = blockIdx.y * BN_;
    const int r15 = lane & 15, kc = lane >> 4;
    f32x4 acc[4][NI];
    #pragma unroll
    for (int mi = 0; mi < 4; ++mi)
        #pragma unroll
        for (int ni = 0; ni < NI; ++ni)
            acc[mi][ni] = (f32x4){0.f, 0.f, 0.f, 0.f};

    const int KT = NTERM * K;
    for (int kp = 0; kp < KT; kp += 64) {
        int seg = (NTERM == 3) ? ((kp >= 2 * K) ? 2 : ((kp >= K) ? 1 : 0))
                               : ((kp >= K) ? 1 : 0);
        int k0 = kp - seg * K;
        const __hip_bfloat16* Ab = (seg == 1) ? Al : Ah;
        const __hip_bfloat16* Bb = (NTERM == 3 && seg == 2) ? Wl : Wh;
        #pragma unroll
        for (int i = 0; i < 4; ++i) {
            int slot = i * 256 + t;
            int row = slot >> 3, cp = slot & 7;
            int cl = cp ^ (row & 7);
            gload_lds16(Ab + (size_t)(bm + row) * K + k0 + cl * 8, As + slot * 8);
        }
        #pragma unroll
        for (int i = 0; i < BN_ / 32; ++i) {
            int slot = i * 256 + t;
            int row = slot >> 3, cp = slot & 7;
            int cl = cp ^ (row & 7);
            gload_lds16(Bb + (size_t)(bn + row) * K + k0 + cl * 8, Bs + slot * 8);
        }
        __syncthreads();
        #pragma unroll
        for (int kk = 0; kk < 2; ++kk) {
            bf16x8 a[4], b[NI];
            #pragma unroll
            for (int mi = 0; mi < 4; ++mi) {
                int row = wm * 64 + mi * 16 + r15;
                int sl = ((kk << 2) | kc) ^ (row & 7);
                a[mi] = *reinterpret_cast<const bf16x8*>(As + row * 64 + sl * 8);
            }
            #pragma unroll
            for (int ni = 0; ni < NI; ++ni) {
                int row = wn * (BN_ / 2) + ni * 16 + r15;
                int sl = ((kk << 2) | kc) ^ (row & 7);
                b[ni] = *reinterpret_cast<const bf16x8*>(Bs + row * 64 + sl * 8);
            }
            #pragma unroll
            for (int mi = 0; mi < 4; ++mi)
                #pragma unroll
                for (int ni = 0; ni < NI; ++ni)
                    acc[mi][ni] = __builtin_amdgcn_mfma_f32_16x16x32_bf16(a[mi], b[ni], acc[mi][ni], 0, 0, 0);
        }
        __syncthreads();
    }

    const int rq = lane >> 4;
    #pragma unroll
    for (int mi = 0; mi < 4; ++mi) {
        #pragma unroll
        for (int ni = 0; ni < NI; ++ni) {
            int n = bn + wn * (BN_ / 2) + ni * 16 + r15;
            float bz = bias[n];
            #pragma unroll
            for (int r = 0; r < 4; ++r) {
                int m = bm + wm * 64 + mi * 16 + rq * 4 + r;
                float v = acc[mi][ni][r] + bz;
                if constexpr (OUTMODE == 0) {
                    C[(size_t)m * N + n] = v;
                } else {
                    float g = gelu_f(v);
                    __hip_bfloat16 hb, lb; split_hl(g, hb, lb);
                    Oh[(size_t)m * N + n] = hb;
                    Ol[(size_t)m * N + n] = lb;
                }
            }
        }
    }
}

// ------ sparsity measure, wave-parallel: 16 lanes per query row ------------
// Each 16-lane group owns one l; lane holds float4 of Q; the 35 sampled
// K-rows become independent coalesced float4 gathers + 4-level shfl reduce.
__global__ __launch_bounds__(512) void mscore_wave(const float* __restrict__ QKV,
                                                   const int* __restrict__ idx,
                                                   float* __restrict__ MX,
                                                   float* __restrict__ SM) {
    int bh = blockIdx.x;                 // 64
    int b = bh >> 3, h = bh & 7;
    int t = threadIdx.x;
    int wv = t >> 6, lane = t & 63;
    int r = lane >> 4;                   // row-in-wave 0..3
    int d4 = lane & 15;                  // float4 slot within row
    int l = blockIdx.y * 32 + wv * 4 + r;   // blockIdx.y 0..31
    const float* qbase = QKV + ((size_t)(b * SQ + l)) * QKVD + h * DH;
    float4 q = reinterpret_cast<const float4*>(qbase)[d4];
    const float* Kbase = QKV + (size_t)b * SQ * QKVD + DM + h * DH;
    const int* ib = idx + l * NTOP;
    float mx = -INFINITY, sm = 0.f;
    #pragma unroll 7
    for (int s = 0; s < NTOP; ++s) {
        int ki = ib[s];
        float4 kv = reinterpret_cast<const float4*>(Kbase + (size_t)ki * QKVD)[d4];
        float d = q.x * kv.x + q.y * kv.y + q.z * kv.z + q.w * kv.w;
        #pragma unroll
        for (int off = 8; off; off >>= 1) d += __shfl_xor(d, off);
        mx = fmaxf(mx, d);
        sm += d;
    }
    if (d4 == 0) {
        MX[bh * SQ + l] = mx;
        SM[bh * SQ + l] = sm;
    }
}

// --------- top-35: register values + wave shfl argmax ----------------------
__global__ __launch_bounds__(256) void topk_kernel(const float* __restrict__ MX,
                                                   const float* __restrict__ SM,
                                                   int* __restrict__ Mtop) {
    int bh = blockIdx.x;
    int t = threadIdx.x, w = t >> 6, lane = t & 63;
    float v[4];
    #pragma unroll
    for (int j = 0; j < 4; ++j) {
        int i = j * 256 + t;
        size_t o = (size_t)bh * SQ + i;
        v[j] = MX[o] - SM[o] * (1.0f / (float)SQ);
    }
    __shared__ float swv[4];
    __shared__ int swi[4];
    __shared__ int winner;
    for (int u = 0; u < NTOP; ++u) {
        float bv = v[0]; int bj = 0;
        #pragma unroll
        for (int j = 1; j < 4; ++j)
            if (v[j] > bv) { bv = v[j]; bj = j; }
        int bi = bj * 256 + t;
        #pragma unroll
        for (int off = 32; off; off >>= 1) {
            float ov = __shfl_xor(bv, off);
            int oi = __shfl_xor(bi, off);
            if (ov > bv || (ov == bv && oi < bi)) { bv = ov; bi = oi; }
        }
        if (lane == 0) { swv[w] = bv; swi[w] = bi; }
        __syncthreads();
        if (t == 0) {
            float gv = swv[0]; int gi = swi[0];
            #pragma unroll
            for (int k = 1; k < 4; ++k)
                if (swv[k] > gv || (swv[k] == gv && swi[k] < gi)) { gv = swv[k]; gi = swi[k]; }
            Mtop[bh * NTOP + u] = gi;
            winner = gi;
        }
        __syncthreads();
        int wi = winner;
        if ((wi & 255) == t) v[wi >> 8] = -INFINITY;
    }
}

// ------ split-K flash attention partials: 8 splits x 64 bh -----------------
__global__ __launch_bounds__(512) void attn_part(const float* __restrict__ QKV,
                                                 const int* __restrict__ Mtop,
                                                 float* __restrict__ PACC,
                                                 float* __restrict__ PM,
                                                 float* __restrict__ PL) {
    __shared__ float Qs[NTOP][68];
    __shared__ float Kt[64][68];
    __shared__ float Vt[64][68];
    __shared__ float St[NTOP][64];
    __shared__ float mS[NTOP], lS[NTOP], fS[NTOP];
    __shared__ int qidx[NTOP];
    int bh = blockIdx.x, ks = blockIdx.y;
    int b = bh >> 3, h = bh & 7;
    int t = threadIdx.x, w = t >> 6, lane = t & 63;
    if (t < NTOP) { qidx[t] = Mtop[bh * NTOP + t]; mS[t] = -INFINITY; lS[t] = 0.f; }
    __syncthreads();
    for (int u = w; u < NTOP; u += 8)
        Qs[u][lane] = QKV[((size_t)(b * SQ + qidx[u])) * QKVD + h * DH + lane];
    float a_acc[5] = {0.f, 0.f, 0.f, 0.f, 0.f};
    __syncthreads();
    for (int tk = ks * 2; tk < ks * 2 + 2; ++tk) {
        #pragma unroll
        for (int i = 0; i < 2; ++i) {
            int idx4 = i * 512 + t;            // 0..1023
            int kr = idx4 >> 4, c4 = (idx4 & 15) << 2;
            const float* kp = QKV + ((size_t)(b * SQ + tk * 64 + kr)) * QKVD + DM + h * DH + c4;
            *reinterpret_cast<float4*>(&Kt[kr][c4]) = *reinterpret_cast<const float4*>(kp);
            *reinterpret_cast<float4*>(&Vt[kr][c4]) = *reinterpret_cast<const float4*>(kp + DM);
        }
        __syncthreads();
        float sv[5] = {0.f, 0.f, 0.f, 0.f, 0.f};
        #pragma unroll
        for (int d4 = 0; d4 < 16; ++d4) {
            float4 kv = *reinterpret_cast<const float4*>(&Kt[lane][d4 << 2]);
            #pragma unroll
            for (int j = 0; j < 5; ++j) {
                int u = w + 8 * j;
                if (u < NTOP) {
                    float4 qv = *reinterpret_cast<const float4*>(&Qs[u][d4 << 2]);
                    sv[j] += qv.x * kv.x + qv.y * kv.y + qv.z * kv.z + qv.w * kv.w;
                }
            }
        }
        #pragma unroll
        for (int j = 0; j < 5; ++j) {
            int u = w + 8 * j;
            if (u < NTOP) {
                float s = sv[j] * 0.125f;
                float mx = s;
                #pragma unroll
                for (int off = 32; off; off >>= 1) mx = fmaxf(mx, __shfl_xor(mx, off));
                float m_old = mS[u];
                float m_new = fmaxf(m_old, mx);
                float e = expf(s - m_new);
                float sum = e;
                #pragma unroll
                for (int off = 32; off; off >>= 1) sum += __shfl_xor(sum, off);
                St[u][lane] = e;
                if (lane == 0) {
                    float f = expf(m_old - m_new);
                    fS[u] = f;
                    lS[u] = lS[u] * f + sum;
                    mS[u] = m_new;
                }
            }
        }
        __syncthreads();
        #pragma unroll
        for (int j = 0; j < 5; ++j) {
            int u = w + 8 * j;
            if (u < NTOP) {
                float acc = a_acc[j] * fS[u];
                for (int k = 0; k < 64; ++k)
                    acc += St[u][k] * Vt[k][lane];
                a_acc[j] = acc;
            }
        }
        __syncthreads();
    }
    #pragma unroll
    for (int j = 0; j < 5; ++j) {
        int u = w + 8 * j;
        if (u < NTOP) {
            PACC[(((size_t)bh * KSPLIT + ks) * NTOP + u) * DH + lane] = a_acc[j];
            if (lane == 0) {
                PM[((size_t)bh * KSPLIT + ks) * NTOP + u] = mS[u];
                PL[((size_t)bh * KSPLIT + ks) * NTOP + u] = lS[u];
            }
        }
    }
}

// ------- combine attention partials + scatter into context (bf16 h/l) ------
__global__ __launch_bounds__(512) void attn_comb(const float* __restrict__ PACC,
                                                 const float* __restrict__ PM,
                                                 const float* __restrict__ PL,
                                                 const int* __restrict__ Mtop,
                                                 __hip_bfloat16* __restrict__ ch,
                                                 __hip_bfloat16* __restrict__ cl) {
    int bh = blockIdx.x;
    int b = bh >> 3, h = bh & 7;
    int t = threadIdx.x, w = t >> 6, lane = t & 63;
    #pragma unroll
    for (int j = 0; j < 5; ++j) {
        int u = w + 8 * j;
        if (u < NTOP) {
            float M = -INFINITY;
            #pragma unroll
            for (int i = 0; i < KSPLIT; ++i)
                M = fmaxf(M, PM[((size_t)bh * KSPLIT + i) * NTOP + u]);
            float lsum = 0.f, acc = 0.f;
            #pragma unroll
            for (int i = 0; i < KSPLIT; ++i) {
                float f = expf(PM[((size_t)bh * KSPLIT + i) * NTOP + u] - M);
                lsum += f * PL[((size_t)bh * KSPLIT + i) * NTOP + u];
                acc += f * PACC[(((size_t)bh * KSPLIT + i) * NTOP + u) * DH + lane];
            }
            float v = acc / lsum;
            int l = Mtop[bh * NTOP + u];
            size_t o = ((size_t)(b * SQ + l)) * DM + h * DH + lane;
            __hip_bfloat16 hb, lb; split_hl(v, hb, lb);
            ch[o] = hb; cl[o] = lb;
        }
    }
}

// ---------------- V mean: two-stage ----------------------------------------
__global__ __launch_bounds__(256) void meanv_part(const float* __restrict__ QKV,
                                                  float* __restrict__ part) {
    int bh = blockIdx.x, sp = blockIdx.y;   // 64 x 8
    int t = threadIdx.x;
    int b = bh >> 3, h = bh & 7;
    int dh = t & 63, chunk = t >> 6;        // 4 chunks x 32 rows
    int s0 = sp * 128 + chunk * 32;
    float acc = 0.f;
    for (int s = s0; s < s0 + 32; ++s)
        acc += QKV[((size_t)(b * SQ + s)) * QKVD + 2 * DM + h * DH + dh];
    __shared__ float red[256];
    red[t] = acc; __syncthreads();
    if (t < 64)
        part[((size_t)bh * 8 + sp) * DH + dh] =
            red[t] + red[64 + t] + red[128 + t] + red[192 + t];
}

__global__ void meanv_comb(const float* __restrict__ part, float* __restrict__ meanV) {
    int bh = blockIdx.x;
    int t = threadIdx.x;  // 64
    float s = 0.f;
    #pragma unroll
    for (int i = 0; i < 8; ++i) s += part[((size_t)bh * 8 + i) * DH + t];
    meanV[bh * DH + t] = s * (1.0f / (float)SQ);
}

// ------- build context directly as bf16 hi/lo: broadcast meanV -------------
__global__ void ctxfill2_kernel(const float* __restrict__ meanV,
                                __hip_bfloat16* __restrict__ ch,
                                __hip_bfloat16* __restrict__ cl) {
    int n = blockIdx.x * 256 + threadIdx.x;   // 0 .. 4194303
    int d = n & 511;
    int row = n >> 9;
    int b = row >> 10;
    float v = meanV[((b << 3) + (d >> 6)) * DH + (d & 63)];
    __hip_bfloat16 hb, lb; split_hl(v, hb, lb);
    ch[n] = hb; cl[n] = lb;
}

// ---------------- residual add + LayerNorm (+fused split) ------------------
__global__ __launch_bounds__(256) void add_ln_kernel(const float* __restrict__ Av,
                                                     const float* __restrict__ Bv,
                                                     const float* __restrict__ g,
                                                     const float* __restrict__ be,
                                                     float* __restrict__ out,
                                                     __hip_bfloat16* __restrict__ oh,
                                                     __hip_bfloat16* __restrict__ ol) {
    int row = blockIdx.x;
    int t = threadIdx.x;
    size_t base = (size_t)row * DM;
    float v0 = Av[base + t] + Bv[base + t];
    float v1 = Av[base + 256 + t] + Bv[base + 256 + t];
    __shared__ float r1[256], r2[256];
    r1[t] = v0 + v1; r2[t] = v0 * v0 + v1 * v1;
    __syncthreads();
    for (int s = 128; s > 0; s >>= 1) {
        if (t < s) { r1[t] += r1[t + s]; r2[t] += r2[t + s]; }
        __syncthreads();
    }
    float mu = r1[0] * (1.0f / (float)DM);
    float var = r2[0] * (1.0f / (float)DM) - mu * mu;
    float rs = rsqrtf(var + EPSF);
    float o0 = (v0 - mu) * rs * g[t] + be[t];
    float o1 = (v1 - mu) * rs * g[t + 256] + be[t + 256];
    out[base + t] = o0;
    out[base + 256 + t] = o1;
    __hip_bfloat16 hb, lb;
    split_hl(o0, hb, lb); oh[base + t] = hb; ol[base + t] = lb;
    split_hl(o1, hb, lb); oh[base + 256 + t] = hb; ol[base + 256 + t] = lb;
}

// ---------------- final LN + GELU + mask -----------------------------------
__global__ __launch_bounds__(256) void final_kernel(const float* __restrict__ X,
                                                    const float* __restrict__ g,
                                                    const float* __restrict__ be,
                                                    const float* __restrict__ mark,
                                                    float* __restrict__ act) {
    int row = blockIdx.x;
    int t = threadIdx.x;
    size_t base = (size_t)row * DM;
    float v0 = X[base + t];
    float v1 = X[base + 256 + t];
    __shared__ float r1[256], r2[256];
    r1[t] = v0 + v1; r2[t] = v0 * v0 + v1 * v1;
    __syncthreads();
    for (int s = 128; s > 0; s >>= 1) {
        if (t < s) { r1[t] += r1[t + s]; r2[t] += r2[t + s]; }
        __syncthreads();
    }
    float mu = r1[0] * (1.0f / (float)DM);
    float var = r2[0] * (1.0f / (float)DM) - mu * mu;
    float rs = rsqrtf(var + EPSF);
    float mk = mark[row];
    float a0 = (v0 - mu) * rs * g[t] + be[t];
    float a1 = (v1 - mu) * rs * g[t + 256] + be[t + 256];
    act[base + t] = gelu_f(a0) * mk;
    act[base + 256 + t] = gelu_f(a1) * mk;
}

// ---------------- final projection: two-stage ------------------------------
__global__ __launch_bounds__(256) void proj1_kernel(const float* __restrict__ act,
                                                    const float* __restrict__ pw,
                                                    float* __restrict__ part) {
    int bc = blockIdx.x;      // 40
    int sg = blockIdx.y;      // 16
    int b = bc / 5, c = bc % 5;
    const float4* a = reinterpret_cast<const float4*>(act + (size_t)b * (SQ * DM) + sg * 32768);
    const float4* w = reinterpret_cast<const float4*>(pw + (size_t)c * (SQ * DM) + sg * 32768);
    float s = 0.f;
    for (int i = threadIdx.x; i < 8192; i += 256) {
        float4 av = a[i], wv = w[i];
        s += av.x * wv.x + av.y * wv.y + av.z * wv.z + av.w * wv.w;
    }
    __shared__ float red[256];
    red[threadIdx.x] = s; __syncthreads();
    for (int sft = 128; sft > 0; sft >>= 1) {
        if (threadIdx.x < sft) red[threadIdx.x] += red[threadIdx.x + sft];
        __syncthreads();
    }
    if (threadIdx.x == 0) part[bc * 16 + sg] = red[0];
}

__global__ void proj2_kernel(const float* __restrict__ part, const float* __restrict__ pb,
                             float* __restrict__ out) {
    int t = threadIdx.x;  // 64
    if (t < 40) {
        float s = 0.f;
        #pragma unroll
        for (int i = 0; i < 16; ++i) s += part[t * 16 + i];
        out[t] = s + pb[t % 5];
    }
}

// ---------------------------------------------------------------------------
extern "C" void kernel_launch(void* const* d_in, const int* in_sizes, int n_in,
                              void* d_out, int out_size, void* d_ws, size_t ws_size,
                              hipStream_t stream) {
    (void)in_sizes; (void)n_in; (void)out_size; (void)ws_size;

    const float* x_enc      = (const float*)d_in[0];
    const float* x_mark_enc = (const float*)d_in[1];
    const float* token_k    = (const float*)d_in[2];
    const float* Wq = (const float*)d_in[3];
    const float* bq = (const float*)d_in[4];
    const float* Wk = (const float*)d_in[5];
    const float* bk = (const float*)d_in[6];
    const float* Wv = (const float*)d_in[7];
    const float* bv = (const float*)d_in[8];
    const float* Wo = (const float*)d_in[9];
    const float* bo = (const float*)d_in[10];
    const float* c1w = (const float*)d_in[11];
    const float* c1b = (const float*)d_in[12];
    const float* c2w = (const float*)d_in[13];
    const float* c2b = (const float*)d_in[14];
    const float* g1 = (const float*)d_in[15];
    const float* b1 = (const float*)d_in[16];
    const float* g2 = (const float*)d_in[17];
    const float* b2 = (const float*)d_in[18];
    const float* gf = (const float*)d_in[19];
    const float* bf = (const float*)d_in[20];
    const float* proj_w = (const float*)d_in[21];
    const float* proj_b = (const float*)d_in[22];
    float* out = (float*)d_out;

    const size_t MB = 1024 * 1024;
    char* wsb = (char*)d_ws;
    float* X    = (float*)(wsb);                  // 0..16
    float* QKVp = (float*)(wsb + 16 * MB);        // 16..64 (8192x1536 fp32)
    __hip_bfloat16* CTXh = (__hip_bfloat16*)(wsb + 16 * MB);  // 16..24
    __hip_bfloat16* CTXl = (__hip_bfloat16*)(wsb + 24 * MB);  // 24..32
    __hip_bfloat16* Yh   = (__hip_bfloat16*)(wsb);            // 0..32 (X+CTX dead)
    __hip_bfloat16* Yl   = (__hip_bfloat16*)(wsb + 32 * MB);  // 32..64
    float* X1p  = (float*)(wsb + 64 * MB);        // 64..80
    float* NXp  = (float*)(wsb + 80 * MB);        // 80..96
    __hip_bfloat16* Xh  = (__hip_bfloat16*)(wsb + 96 * MB);   // 96..104
    __hip_bfloat16* Xl  = (__hip_bfloat16*)(wsb + 104 * MB);  // 104..112
    __hip_bfloat16* X1h = (__hip_bfloat16*)(wsb + 112 * MB);  // 112..120
    __hip_bfloat16* X1l = (__hip_bfloat16*)(wsb + 120 * MB);  // 120..128
    __hip_bfloat16* WhA = (__hip_bfloat16*)(wsb + 128 * MB);  // 128..130
    __hip_bfloat16* WlA = (__hip_bfloat16*)(wsb + 130 * MB);  // 130..132
    __hip_bfloat16* WhB = (__hip_bfloat16*)(wsb + 132 * MB);  // 132..134
    __hip_bfloat16* WlB = (__hip_bfloat16*)(wsb + 134 * MB);  // 134..136
    char* smal = wsb + 136 * MB;
    float* biasC  = (float*)(smal);                           // 8 KB
    int*   IDX    = (int*)(smal + 8 * 1024);                  // 160 KB
    int*   MTOP   = (int*)(smal + 168 * 1024);                // 16 KB
    float* MEANV  = (float*)(smal + 184 * 1024);              // 16 KB
    float* PART   = (float*)(smal + 200 * 1024);              // 8 KB
    float* MVPART = (float*)(smal + 208 * 1024);              // 128 KB + pad
    float* MX     = (float*)(smal + 384 * 1024);              // 256 KB (64x1024)
    float* SM     = (float*)(smal + 2176 * 1024);             // 256 KB
    float* PM     = (float*)(smal + 3968 * 1024);             // 96 KB
    float* PL     = (float*)(smal + 4064 * 1024);             // 96 KB
    float* PACC   = (float*)(smal + 4160 * 1024);             // 4.6 MB

    embed_kernel<<<ROWS, 256, 0, stream>>>(x_enc, token_k, X, Xh, Xl);

    for (int lyr = 0; lyr < 3; ++lyr) {
        const float* Wq_l = Wq + (size_t)lyr * DM * DM;
        const float* bq_l = bq + (size_t)lyr * DM;
        const float* Wk_l = Wk + (size_t)lyr * DM * DM;
        const float* bk_l = bk + (size_t)lyr * DM;
        const float* Wv_l = Wv + (size_t)lyr * DM * DM;
        const float* bv_l = bv + (size_t)lyr * DM;
        const float* Wo_l = Wo + (size_t)lyr * DM * DM;
        const float* bo_l = bo + (size_t)lyr * DM;
        const float* c1w_l = c1w + (size_t)lyr * DFF * DM;
        const float* c1b_l = c1b + (size_t)lyr * DFF;
        const float* c2w_l = c2w + (size_t)lyr * DM * DFF;
        const float* c2b_l = c2b + (size_t)lyr * DM;
        const float* g1_l = g1 + (size_t)lyr * DM;
        const float* b1_l = b1 + (size_t)lyr * DM;
        const float* g2_l = g2 + (size_t)lyr * DM;
        const float* b2_l = b2 + (size_t)lyr * DM;

        // ---- weight split A: QKV -> WhA, Wo -> WhB, bias concat ----
        wsplitA_kernel<<<1025, 256, 0, stream>>>(Wq_l, Wk_l, Wv_l, Wo_l,
                                                 bq_l, bk_l, bv_l,
                                                 WhA, WlA, WhB, WlB, biasC);
        // ---- fused QKV projection (N=1536), 3-term (selection-exact) ----
        mfma_gemm<128, 0, 3><<<dim3(ROWS / 128, QKVD / 128), 256, 0, stream>>>(
            Xh, Xl, WhA, WlA, biasC, QKVp, nullptr, nullptr, ROWS, QKVD, DM);

        // ---- ProbSparse attention ----
        idx_kernel<<<(SQ * NTOP + 255) / 256, 256, 0, stream>>>(lyr, IDX);
        mscore_wave<<<dim3(64, 32), 512, 0, stream>>>(QKVp, IDX, MX, SM);
        topk_kernel<<<64, 256, 0, stream>>>(MX, SM, MTOP);
        attn_part<<<dim3(64, KSPLIT), 512, 0, stream>>>(QKVp, MTOP, PACC, PM, PL);
        meanv_part<<<dim3(64, 8), 256, 0, stream>>>(QKVp, MVPART);
        meanv_comb<<<64, 64, 0, stream>>>(MVPART, MEANV);
        // QKV fp32 dead now; write context straight into its region as h/l
        ctxfill2_kernel<<<(ROWS * DM) / 256, 256, 0, stream>>>(MEANV, CTXh, CTXl);
        attn_comb<<<64, 512, 0, stream>>>(PACC, PM, PL, MTOP, CTXh, CTXl);

        // ---- attention out-projection (Wo in WhB), 2-term value path ----
        mfma_gemm<64, 0, 2><<<dim3(ROWS / 128, DM / 64), 256, 0, stream>>>(
            CTXh, CTXl, WhB, WlB, bo_l, NXp, nullptr, nullptr, ROWS, DM, DM);
        add_ln_kernel<<<ROWS, 256, 0, stream>>>(X, NXp, g1_l, b1_l, X1p, X1h, X1l);

        // ---- weight split B: c1w -> WhA, c2w -> WhB ----
        wsplitB_kernel<<<2048, 256, 0, stream>>>(c1w_l, c2w_l, WhA, WlA, WhB, WlB);
        // ---- FFN (Y occupies 0..64MB where X/CTX/QKV are dead), 2-term ----
        mfma_gemm<128, 2, 2><<<dim3(ROWS / 128, DFF / 128), 256, 0, stream>>>(
            X1h, X1l, WhA, WlA, c1b_l, nullptr, Yh, Yl, ROWS, DFF, DM);
        mfma_gemm<64, 0, 2><<<dim3(ROWS / 128, DM / 64), 256, 0, stream>>>(
            Yh, Yl, WhB, WlB, c2b_l, NXp, nullptr, nullptr, ROWS, DM, DFF);
        add_ln_kernel<<<ROWS, 256, 0, stream>>>(X1p, NXp, g2_l, b2_l, X, Xh, Xl);
    }

    final_kernel<<<ROWS, 256, 0, stream>>>(X, gf, bf, x_mark_enc, (float*)QKVp);
    proj1_kernel<<<dim3(40, 16), 256, 0, stream>>>((float*)QKVp, proj_w, PART);
    proj2_kernel<<<1, 64, 0, stream>>>(PART, proj_b, out);
}